// Round 1
// baseline (4918.251 us; speedup 1.0000x reference)
//
#include <hip/hip_runtime.h>

#define M_NODES 100000
#define N_EDGES_C 800000
#define IN_DIM_C 128
#define HID_C 256
#define N_GRAPHS_C 256
#define BN_EPS_C 1e-5f

// ---------------- elementwise helpers ----------------
__global__ void copy_f4(const float4* __restrict__ src, float4* __restrict__ dst, int n4) {
    int i = blockIdx.x * blockDim.x + threadIdx.x;
    if (i < n4) dst[i] = src[i];
}

__global__ void zero_f(float* __restrict__ p, int n) {
    int i = blockIdx.x * blockDim.x + threadIdx.x;
    if (i < n) p[i] = 0.f;
}

// ---------------- scatter-add over edges ----------------
// thread -> (edge e, feature-quad f4). Consecutive lanes cover consecutive
// features => coalesced gather; atomics go to consecutive addresses.
__global__ void scatter_add(const float* __restrict__ h, float* __restrict__ hsum,
                            const int* __restrict__ src, const int* __restrict__ dst,
                            int logF4) {
    long long idx = (long long)blockIdx.x * blockDim.x + threadIdx.x;
    int F4 = 1 << logF4;
    long long e = idx >> logF4;
    int f4 = (int)(idx & (F4 - 1));
    if (e >= N_EDGES_C) return;
    int s = src[e], d = dst[e];
    float4 v = ((const float4*)h)[(long long)s * F4 + f4];
    float* p = hsum + (((long long)d * F4 + f4) << 2);
    atomicAdd(p + 0, v.x);
    atomicAdd(p + 1, v.y);
    atomicAdd(p + 2, v.z);
    atomicAdd(p + 3, v.w);
}

// ---------------- fp32 tiled GEMM: C[M,256] = A[M,K] @ W[K,256] (+bias, relu) ----------------
// BM=BN=128, BK=16, 256 threads, 8x8 per thread.
template <int K>
__global__ __launch_bounds__(256) void gemm_kernel(const float* __restrict__ A,
                                                   const float* __restrict__ W,
                                                   const float* __restrict__ bias,
                                                   float* __restrict__ Cout,
                                                   int M, int do_relu) {
    __shared__ float As[16][132];   // k-major, padded
    __shared__ float Bs[16][128];

    const int tid = threadIdx.x;
    const int tx = tid & 15, ty = tid >> 4;
    const int gm = blockIdx.y * 128;
    const int gn = blockIdx.x * 128;

    float acc[8][8];
#pragma unroll
    for (int i = 0; i < 8; ++i)
#pragma unroll
        for (int j = 0; j < 8; ++j) acc[i][j] = 0.f;

    for (int k0 = 0; k0 < K; k0 += 16) {
        // load A tile 128x16 (transposed into LDS), 2 float4 per thread
#pragma unroll
        for (int l = 0; l < 2; ++l) {
            int t = tid + l * 256;        // 0..511
            int r = t >> 2;               // 0..127
            int kq = t & 3;               // 0..3
            int row = gm + r;
            if (row >= M) row = M - 1;
            float4 v = *(const float4*)(A + (long long)row * K + k0 + kq * 4);
            As[kq * 4 + 0][r] = v.x;
            As[kq * 4 + 1][r] = v.y;
            As[kq * 4 + 2][r] = v.z;
            As[kq * 4 + 3][r] = v.w;
        }
        // load B tile 16x128, 2 float4 per thread
#pragma unroll
        for (int l = 0; l < 2; ++l) {
            int t = tid + l * 256;
            int kk = t >> 5;              // 0..15
            int c = t & 31;               // 0..31
            *(float4*)&Bs[kk][c * 4] = *(const float4*)(W + (long long)(k0 + kk) * HID_C + gn + c * 4);
        }
        __syncthreads();
#pragma unroll
        for (int kk = 0; kk < 16; ++kk) {
            float a[8], b[8];
            *(float4*)&a[0] = *(const float4*)&As[kk][ty * 8];
            *(float4*)&a[4] = *(const float4*)&As[kk][ty * 8 + 4];
            *(float4*)&b[0] = *(const float4*)&Bs[kk][tx * 8];
            *(float4*)&b[4] = *(const float4*)&Bs[kk][tx * 8 + 4];
#pragma unroll
            for (int i = 0; i < 8; ++i)
#pragma unroll
                for (int j = 0; j < 8; ++j) acc[i][j] = fmaf(a[i], b[j], acc[i][j]);
        }
        __syncthreads();
    }

#pragma unroll
    for (int i = 0; i < 8; ++i) {
        int row = gm + ty * 8 + i;
        if (row < M) {
            float* cp = Cout + (long long)row * HID_C + gn + tx * 8;
#pragma unroll
            for (int jj = 0; jj < 2; ++jj) {
                int col = gn + tx * 8 + jj * 4;
                float4 v;
                v.x = acc[i][jj * 4 + 0] + bias[col + 0];
                v.y = acc[i][jj * 4 + 1] + bias[col + 1];
                v.z = acc[i][jj * 4 + 2] + bias[col + 2];
                v.w = acc[i][jj * 4 + 3] + bias[col + 3];
                if (do_relu) {
                    v.x = fmaxf(v.x, 0.f); v.y = fmaxf(v.y, 0.f);
                    v.z = fmaxf(v.z, 0.f); v.w = fmaxf(v.w, 0.f);
                }
                *(float4*)(cp + jj * 4) = v;
            }
        }
    }
}

// ---------------- BatchNorm ----------------
__global__ void bn_stats(const float* __restrict__ h, float* __restrict__ sums, int M) {
    int f = threadIdx.x;  // 256 features
    float s = 0.f, s2 = 0.f;
    for (int r = blockIdx.x; r < M; r += gridDim.x) {
        float v = h[(long long)r * HID_C + f];
        s += v;
        s2 += v * v;
    }
    atomicAdd(&sums[f], s);
    atomicAdd(&sums[HID_C + f], s2);
}

__global__ void bn_finalize(const float* __restrict__ sums, const float* __restrict__ gamma,
                            const float* __restrict__ beta, float* __restrict__ ss) {
    int f = threadIdx.x;
    float mean = sums[f] * (1.0f / M_NODES);
    float var = sums[HID_C + f] * (1.0f / M_NODES) - mean * mean;
    float sc = gamma[f] * rsqrtf(var + BN_EPS_C);
    ss[f] = sc;
    ss[HID_C + f] = beta[f] - mean * sc;
}

// out1 = relu(in*scale+shift); optionally out2 = same (next layer's hsum init)
__global__ void bn_apply_relu(const float4* __restrict__ in, const float* __restrict__ ss,
                              float4* __restrict__ out1, float4* __restrict__ out2, int n4) {
    int i = blockIdx.x * blockDim.x + threadIdx.x;
    if (i >= n4) return;
    int f = (i & 63) << 2;  // feature index of .x
    float4 v = in[i];
    float4 r;
    r.x = fmaxf(v.x * ss[f + 0] + ss[HID_C + f + 0], 0.f);
    r.y = fmaxf(v.y * ss[f + 1] + ss[HID_C + f + 1], 0.f);
    r.z = fmaxf(v.z * ss[f + 2] + ss[HID_C + f + 2], 0.f);
    r.w = fmaxf(v.w * ss[f + 3] + ss[HID_C + f + 3], 0.f);
    out1[i] = r;
    if (out2) out2[i] = r;
}

// ---------------- pooling ----------------
#define POOL_ROWS 391  // 256 blocks cover 100096 rows
__global__ void pool_kernel(const float* __restrict__ h, const int* __restrict__ batch,
                            float* __restrict__ sums, int M) {
    int f = threadIdx.x;
    int r0 = blockIdx.x * POOL_ROWS;
    if (r0 >= M) return;
    int r1 = r0 + POOL_ROWS;
    if (r1 > M) r1 = M;
    int cur = batch[r0];
    float acc = 0.f;
    for (int r = r0; r < r1; ++r) {
        int g = batch[r];
        if (g != cur) {
            atomicAdd(&sums[(long long)cur * HID_C + f], acc);
            acc = 0.f;
            cur = g;
        }
        acc += h[(long long)r * HID_C + f];
    }
    atomicAdd(&sums[(long long)cur * HID_C + f], acc);
}

__device__ __forceinline__ int lower_bound_i(const int* a, int n, int v) {
    int lo = 0, hi = n;
    while (lo < hi) {
        int mid = (lo + hi) >> 1;
        if (a[mid] < v) lo = mid + 1;
        else hi = mid;
    }
    return lo;
}

__global__ void pool_finalize(const float* __restrict__ sums, const int* __restrict__ batch,
                              float* __restrict__ out) {
    int g = blockIdx.x, f = threadIdx.x;
    int lb = lower_bound_i(batch, M_NODES, g);
    int ub = lower_bound_i(batch, M_NODES, g + 1);
    float cnt = (float)(ub - lb);
    out[(long long)g * HID_C + f] = sums[(long long)g * HID_C + f] / fmaxf(cnt, 1.0f);
}

// ---------------- launch ----------------
extern "C" void kernel_launch(void* const* d_in, const int* in_sizes, int n_in,
                              void* d_out, int out_size, void* d_ws, size_t ws_size,
                              hipStream_t stream) {
    const float* x = (const float*)d_in[0];
    const int* ei = (const int*)d_in[1];
    const int* esrc = ei;
    const int* edst = ei + N_EDGES_C;
    const int* batch = (const int*)d_in[2];
    const float* W1_0 = (const float*)d_in[3];
    const float* b1_0 = (const float*)d_in[4];
    const float* W2_0 = (const float*)d_in[5];
    const float* b2_0 = (const float*)d_in[6];
    const float* g0 = (const float*)d_in[7];
    const float* be0 = (const float*)d_in[8];
    const float* W1_1 = (const float*)d_in[9];
    const float* b1_1 = (const float*)d_in[10];
    const float* W2_1 = (const float*)d_in[11];
    const float* b2_1 = (const float*)d_in[12];
    const float* g1 = (const float*)d_in[13];
    const float* be1 = (const float*)d_in[14];
    float* out = (float*)d_out;

    const long long NH = (long long)M_NODES * HID_C;  // 25.6M floats
    float* B = (float*)d_ws;          // hsum / h2 buffer
    float* C = B + NH;                // hidden / h buffer
    float* bns = C + NH;              // 512
    float* ss = bns + 2 * HID_C;      // 512
    float* psum = ss + 2 * HID_C;     // 65536

    dim3 blk(256);
    dim3 gemm_grid(HID_C / 128, (M_NODES + 127) / 128);

    // ---- Layer 0 ----
    // B = x
    {
        int n4 = M_NODES * IN_DIM_C / 4;
        copy_f4<<<(n4 + 255) / 256, blk, 0, stream>>>((const float4*)x, (float4*)B, n4);
    }
    // B += scatter(x)
    {
        long long tot = (long long)N_EDGES_C * (IN_DIM_C / 4);
        scatter_add<<<(unsigned)((tot + 255) / 256), blk, 0, stream>>>(x, B, esrc, edst, 5);
    }
    gemm_kernel<IN_DIM_C><<<gemm_grid, blk, 0, stream>>>(B, W1_0, b1_0, C, M_NODES, 1);
    gemm_kernel<HID_C><<<gemm_grid, blk, 0, stream>>>(C, W2_0, b2_0, B, M_NODES, 0);
    zero_f<<<2, blk, 0, stream>>>(bns, 2 * HID_C);
    bn_stats<<<1024, blk, 0, stream>>>(B, bns, M_NODES);
    bn_finalize<<<1, blk, 0, stream>>>(bns, g0, be0, ss);
    {
        int n4 = (int)(NH / 4);
        // C = h (layer-1 input), B = hsum init (= h)
        bn_apply_relu<<<(n4 + 255) / 256, blk, 0, stream>>>((const float4*)B, ss,
                                                            (float4*)C, (float4*)B, n4);
    }

    // ---- Layer 1 ----
    {
        long long tot = (long long)N_EDGES_C * (HID_C / 4);
        scatter_add<<<(unsigned)((tot + 255) / 256), blk, 0, stream>>>(C, B, esrc, edst, 6);
    }
    gemm_kernel<HID_C><<<gemm_grid, blk, 0, stream>>>(B, W1_1, b1_1, C, M_NODES, 1);
    gemm_kernel<HID_C><<<gemm_grid, blk, 0, stream>>>(C, W2_1, b2_1, B, M_NODES, 0);
    zero_f<<<2, blk, 0, stream>>>(bns, 2 * HID_C);
    bn_stats<<<1024, blk, 0, stream>>>(B, bns, M_NODES);
    bn_finalize<<<1, blk, 0, stream>>>(bns, g1, be1, ss);
    {
        int n4 = (int)(NH / 4);
        bn_apply_relu<<<(n4 + 255) / 256, blk, 0, stream>>>((const float4*)B, ss,
                                                            (float4*)B, (float4*)nullptr, n4);
    }

    // ---- Pool ----
    zero_f<<<(N_GRAPHS_C * HID_C + 255) / 256, blk, 0, stream>>>(psum, N_GRAPHS_C * HID_C);
    pool_kernel<<<256, blk, 0, stream>>>(B, batch, psum, M_NODES);
    pool_finalize<<<256, blk, 0, stream>>>(psum, batch, out);
}

// Round 2
// 1325.080 us; speedup vs baseline: 3.7117x; 3.7117x over previous
//
#include <hip/hip_runtime.h>

#define M_NODES 100000
#define N_EDGES_C 800000
#define IN_DIM_C 128
#define HID_C 256
#define N_GRAPHS_C 256
#define BN_EPS_C 1e-5f

// ---------------- small helpers ----------------
__global__ void zero_f(float* __restrict__ p, int n) {
    int i = blockIdx.x * blockDim.x + threadIdx.x;
    if (i < n) p[i] = 0.f;
}
__global__ void zero_i(int* __restrict__ p, int n) {
    int i = blockIdx.x * blockDim.x + threadIdx.x;
    if (i < n) p[i] = 0;
}
__global__ void copy_i(const int* __restrict__ s, int* __restrict__ d, int n) {
    int i = blockIdx.x * blockDim.x + threadIdx.x;
    if (i < n) d[i] = s[i];
}

// ---------------- CSR build (once per call; reused by both layers) ----------------
__global__ void csr_count(const int* __restrict__ dst, int* __restrict__ counts) {
    int e = blockIdx.x * blockDim.x + threadIdx.x;
    if (e < N_EDGES_C) atomicAdd(&counts[dst[e]], 1);
}

#define SCAN_THREADS 1024
__global__ __launch_bounds__(SCAN_THREADS) void scan_rowptr(const int* __restrict__ counts,
                                                            int* __restrict__ rowptr) {
    __shared__ int smem[SCAN_THREADS];
    const int t = threadIdx.x;
    const int chunk = (M_NODES + SCAN_THREADS - 1) / SCAN_THREADS;  // 98
    int beg = t * chunk;
    int end = beg + chunk;
    if (beg > M_NODES) beg = M_NODES;
    if (end > M_NODES) end = M_NODES;
    int s = 0;
    for (int i = beg; i < end; ++i) s += counts[i];
    smem[t] = s;
    __syncthreads();
    for (int off = 1; off < SCAN_THREADS; off <<= 1) {
        int add = (t >= off) ? smem[t - off] : 0;
        __syncthreads();
        smem[t] += add;
        __syncthreads();
    }
    int run = smem[t] - s;  // exclusive base for this chunk
    for (int i = beg; i < end; ++i) {
        rowptr[i] = run;
        run += counts[i];
    }
    if (end == M_NODES) rowptr[M_NODES] = run;  // all writers write the same total
}

__global__ void csr_fill(const int* __restrict__ src, const int* __restrict__ dst,
                         int* __restrict__ fillpos, int* __restrict__ csr_src) {
    int e = blockIdx.x * blockDim.x + threadIdx.x;
    if (e >= N_EDGES_C) return;
    int pos = atomicAdd(&fillpos[dst[e]], 1);
    csr_src[pos] = src[e];
}

// ---------------- gather aggregation: out[n] = h[n] + sum_{j->n} h[j] ----------------
// NQ float4-quads per row; NQ consecutive threads own one node.
template <int NQ>
__global__ __launch_bounds__(256) void gather_agg(const float* __restrict__ h,
                                                  const int* __restrict__ rowptr,
                                                  const int* __restrict__ csr_src,
                                                  float* __restrict__ out) {
    int node = blockIdx.x * (256 / NQ) + threadIdx.x / NQ;
    int q = threadIdx.x & (NQ - 1);
    if (node >= M_NODES) return;
    const float4* h4 = (const float4*)h;
    float4 acc = h4[(long long)node * NQ + q];  // self term (GIN eps=0)
    int beg = rowptr[node], end = rowptr[node + 1];
    for (int e = beg; e < end; ++e) {
        int s = csr_src[e];
        float4 v = h4[(long long)s * NQ + q];
        acc.x += v.x; acc.y += v.y; acc.z += v.z; acc.w += v.w;
    }
    ((float4*)out)[(long long)node * NQ + q] = acc;
}

// ---------------- fp32 tiled GEMM: C[M,256] = A[M,K] @ W[K,256] (+bias, relu) ----------------
template <int K>
__global__ __launch_bounds__(256) void gemm_kernel(const float* __restrict__ A,
                                                   const float* __restrict__ W,
                                                   const float* __restrict__ bias,
                                                   float* __restrict__ Cout,
                                                   int M, int do_relu) {
    __shared__ float As[16][132];   // k-major, padded
    __shared__ float Bs[16][128];

    const int tid = threadIdx.x;
    const int tx = tid & 15, ty = tid >> 4;
    const int gm = blockIdx.y * 128;
    const int gn = blockIdx.x * 128;

    float acc[8][8];
#pragma unroll
    for (int i = 0; i < 8; ++i)
#pragma unroll
        for (int j = 0; j < 8; ++j) acc[i][j] = 0.f;

    for (int k0 = 0; k0 < K; k0 += 16) {
#pragma unroll
        for (int l = 0; l < 2; ++l) {
            int t = tid + l * 256;
            int r = t >> 2;
            int kq = t & 3;
            int row = gm + r;
            if (row >= M) row = M - 1;
            float4 v = *(const float4*)(A + (long long)row * K + k0 + kq * 4);
            As[kq * 4 + 0][r] = v.x;
            As[kq * 4 + 1][r] = v.y;
            As[kq * 4 + 2][r] = v.z;
            As[kq * 4 + 3][r] = v.w;
        }
#pragma unroll
        for (int l = 0; l < 2; ++l) {
            int t = tid + l * 256;
            int kk = t >> 5;
            int c = t & 31;
            *(float4*)&Bs[kk][c * 4] = *(const float4*)(W + (long long)(k0 + kk) * HID_C + gn + c * 4);
        }
        __syncthreads();
#pragma unroll
        for (int kk = 0; kk < 16; ++kk) {
            float a[8], b[8];
            *(float4*)&a[0] = *(const float4*)&As[kk][ty * 8];
            *(float4*)&a[4] = *(const float4*)&As[kk][ty * 8 + 4];
            *(float4*)&b[0] = *(const float4*)&Bs[kk][tx * 8];
            *(float4*)&b[4] = *(const float4*)&Bs[kk][tx * 8 + 4];
#pragma unroll
            for (int i = 0; i < 8; ++i)
#pragma unroll
                for (int j = 0; j < 8; ++j) acc[i][j] = fmaf(a[i], b[j], acc[i][j]);
        }
        __syncthreads();
    }

#pragma unroll
    for (int i = 0; i < 8; ++i) {
        int row = gm + ty * 8 + i;
        if (row < M) {
            float* cp = Cout + (long long)row * HID_C + gn + tx * 8;
#pragma unroll
            for (int jj = 0; jj < 2; ++jj) {
                int col = gn + tx * 8 + jj * 4;
                float4 v;
                v.x = acc[i][jj * 4 + 0] + bias[col + 0];
                v.y = acc[i][jj * 4 + 1] + bias[col + 1];
                v.z = acc[i][jj * 4 + 2] + bias[col + 2];
                v.w = acc[i][jj * 4 + 3] + bias[col + 3];
                if (do_relu) {
                    v.x = fmaxf(v.x, 0.f); v.y = fmaxf(v.y, 0.f);
                    v.z = fmaxf(v.z, 0.f); v.w = fmaxf(v.w, 0.f);
                }
                *(float4*)(cp + jj * 4) = v;
            }
        }
    }
}

// ---------------- BatchNorm ----------------
__global__ void bn_stats(const float* __restrict__ h, float* __restrict__ sums, int M) {
    int f = threadIdx.x;
    float s = 0.f, s2 = 0.f;
    for (int r = blockIdx.x; r < M; r += gridDim.x) {
        float v = h[(long long)r * HID_C + f];
        s += v;
        s2 += v * v;
    }
    atomicAdd(&sums[f], s);
    atomicAdd(&sums[HID_C + f], s2);
}

__global__ void bn_finalize(const float* __restrict__ sums, const float* __restrict__ gamma,
                            const float* __restrict__ beta, float* __restrict__ ss) {
    int f = threadIdx.x;
    float mean = sums[f] * (1.0f / M_NODES);
    float var = sums[HID_C + f] * (1.0f / M_NODES) - mean * mean;
    float sc = gamma[f] * rsqrtf(var + BN_EPS_C);
    ss[f] = sc;
    ss[HID_C + f] = beta[f] - mean * sc;
}

__global__ void bn_apply_relu(const float4* __restrict__ in, const float* __restrict__ ss,
                              float4* __restrict__ out, int n4) {
    int i = blockIdx.x * blockDim.x + threadIdx.x;
    if (i >= n4) return;
    int f = (i & 63) << 2;
    float4 v = in[i];
    float4 r;
    r.x = fmaxf(v.x * ss[f + 0] + ss[HID_C + f + 0], 0.f);
    r.y = fmaxf(v.y * ss[f + 1] + ss[HID_C + f + 1], 0.f);
    r.z = fmaxf(v.z * ss[f + 2] + ss[HID_C + f + 2], 0.f);
    r.w = fmaxf(v.w * ss[f + 3] + ss[HID_C + f + 3], 0.f);
    out[i] = r;
}

// ---------------- pooling ----------------
#define POOL_ROWS 391
__global__ void pool_kernel(const float* __restrict__ h, const int* __restrict__ batch,
                            float* __restrict__ sums, int M) {
    int f = threadIdx.x;
    int r0 = blockIdx.x * POOL_ROWS;
    if (r0 >= M) return;
    int r1 = r0 + POOL_ROWS;
    if (r1 > M) r1 = M;
    int cur = batch[r0];
    float acc = 0.f;
    for (int r = r0; r < r1; ++r) {
        int g = batch[r];
        if (g != cur) {
            atomicAdd(&sums[(long long)cur * HID_C + f], acc);
            acc = 0.f;
            cur = g;
        }
        acc += h[(long long)r * HID_C + f];
    }
    atomicAdd(&sums[(long long)cur * HID_C + f], acc);
}

__device__ __forceinline__ int lower_bound_i(const int* a, int n, int v) {
    int lo = 0, hi = n;
    while (lo < hi) {
        int mid = (lo + hi) >> 1;
        if (a[mid] < v) lo = mid + 1;
        else hi = mid;
    }
    return lo;
}

__global__ void pool_finalize(const float* __restrict__ sums, const int* __restrict__ batch,
                              float* __restrict__ out) {
    int g = blockIdx.x, f = threadIdx.x;
    int lb = lower_bound_i(batch, M_NODES, g);
    int ub = lower_bound_i(batch, M_NODES, g + 1);
    float cnt = (float)(ub - lb);
    out[(long long)g * HID_C + f] = sums[(long long)g * HID_C + f] / fmaxf(cnt, 1.0f);
}

// ---------------- launch ----------------
extern "C" void kernel_launch(void* const* d_in, const int* in_sizes, int n_in,
                              void* d_out, int out_size, void* d_ws, size_t ws_size,
                              hipStream_t stream) {
    const float* x = (const float*)d_in[0];
    const int* ei = (const int*)d_in[1];
    const int* esrc = ei;
    const int* edst = ei + N_EDGES_C;
    const int* batch = (const int*)d_in[2];
    const float* W1_0 = (const float*)d_in[3];
    const float* b1_0 = (const float*)d_in[4];
    const float* W2_0 = (const float*)d_in[5];
    const float* b2_0 = (const float*)d_in[6];
    const float* g0 = (const float*)d_in[7];
    const float* be0 = (const float*)d_in[8];
    const float* W1_1 = (const float*)d_in[9];
    const float* b1_1 = (const float*)d_in[10];
    const float* W2_1 = (const float*)d_in[11];
    const float* b2_1 = (const float*)d_in[12];
    const float* g1 = (const float*)d_in[13];
    const float* be1 = (const float*)d_in[14];
    float* out = (float*)d_out;

    const long long NH = (long long)M_NODES * HID_C;  // 25.6M floats
    float* B = (float*)d_ws;              // agg / post-MLP buffer
    float* C = B + NH;                    // hidden buffer
    float* bns = C + NH;                  // 512
    float* ss = bns + 2 * HID_C;          // 512
    int* counts = (int*)(ss + 2 * HID_C); // 100000 (reused as fillpos)
    int* rowptr = counts + M_NODES;       // 100001
    int* csr_src = rowptr + (M_NODES + 1);// 800000
    float* psum = (float*)csr_src;        // aliased: psum used only after last gather

    dim3 blk(256);
    dim3 gemm_grid(HID_C / 128, (M_NODES + 127) / 128);

    // ---- CSR build (shared by both layers) ----
    zero_i<<<(M_NODES + 255) / 256, blk, 0, stream>>>(counts, M_NODES);
    csr_count<<<(N_EDGES_C + 255) / 256, blk, 0, stream>>>(edst, counts);
    scan_rowptr<<<1, SCAN_THREADS, 0, stream>>>(counts, rowptr);
    copy_i<<<(M_NODES + 255) / 256, blk, 0, stream>>>(rowptr, counts, M_NODES);  // counts := fillpos
    csr_fill<<<(N_EDGES_C + 255) / 256, blk, 0, stream>>>(esrc, edst, counts, csr_src);

    // ---- Layer 0 ----
    gather_agg<IN_DIM_C / 4><<<(M_NODES * (IN_DIM_C / 4) + 255) / 256, blk, 0, stream>>>(
        x, rowptr, csr_src, B);
    gemm_kernel<IN_DIM_C><<<gemm_grid, blk, 0, stream>>>(B, W1_0, b1_0, C, M_NODES, 1);
    gemm_kernel<HID_C><<<gemm_grid, blk, 0, stream>>>(C, W2_0, b2_0, B, M_NODES, 0);
    zero_f<<<2, blk, 0, stream>>>(bns, 2 * HID_C);
    bn_stats<<<1024, blk, 0, stream>>>(B, bns, M_NODES);
    bn_finalize<<<1, blk, 0, stream>>>(bns, g0, be0, ss);
    bn_apply_relu<<<(int)((NH / 4 + 255) / 256), blk, 0, stream>>>((const float4*)B, ss,
                                                                   (float4*)C, (int)(NH / 4));

    // ---- Layer 1 ----
    gather_agg<HID_C / 4><<<(M_NODES * (HID_C / 4) + 255) / 256, blk, 0, stream>>>(
        C, rowptr, csr_src, B);
    gemm_kernel<HID_C><<<gemm_grid, blk, 0, stream>>>(B, W1_1, b1_1, C, M_NODES, 1);
    gemm_kernel<HID_C><<<gemm_grid, blk, 0, stream>>>(C, W2_1, b2_1, B, M_NODES, 0);
    zero_f<<<2, blk, 0, stream>>>(bns, 2 * HID_C);
    bn_stats<<<1024, blk, 0, stream>>>(B, bns, M_NODES);
    bn_finalize<<<1, blk, 0, stream>>>(bns, g1, be1, ss);
    bn_apply_relu<<<(int)((NH / 4 + 255) / 256), blk, 0, stream>>>((const float4*)B, ss,
                                                                   (float4*)B, (int)(NH / 4));

    // ---- Pool ----
    zero_f<<<(N_GRAPHS_C * HID_C + 255) / 256, blk, 0, stream>>>(psum, N_GRAPHS_C * HID_C);
    pool_kernel<<<256, blk, 0, stream>>>(B, batch, psum, M_NODES);
    pool_finalize<<<256, blk, 0, stream>>>(psum, batch, out);
}

// Round 3
// 1097.470 us; speedup vs baseline: 4.4814x; 1.2074x over previous
//
#include <hip/hip_runtime.h>

#define M_NODES 100000
#define N_EDGES_C 800000
#define IN_DIM_C 128
#define HID_C 256
#define N_GRAPHS_C 256
#define BN_EPS_C 1e-5f

typedef __attribute__((ext_vector_type(8))) short short8v;
typedef __attribute__((ext_vector_type(4))) float floatx4;

__device__ __forceinline__ unsigned short bf16_rne(float f) {
    union { float f; unsigned u; } x; x.f = f;
    unsigned r = x.u + 0x7FFF + ((x.u >> 16) & 1);
    return (unsigned short)(r >> 16);
}
__device__ __forceinline__ float bf16_to_f(unsigned short h) {
    union { unsigned u; float f; } x; x.u = ((unsigned)h) << 16;
    return x.f;
}

// ---------------- small helpers ----------------
__global__ void zero_f(float* __restrict__ p, int n) {
    int i = blockIdx.x * blockDim.x + threadIdx.x;
    if (i < n) p[i] = 0.f;
}
__global__ void zero_i(int* __restrict__ p, int n) {
    int i = blockIdx.x * blockDim.x + threadIdx.x;
    if (i < n) p[i] = 0;
}
__global__ void copy_i(const int* __restrict__ s, int* __restrict__ d, int n) {
    int i = blockIdx.x * blockDim.x + threadIdx.x;
    if (i < n) d[i] = s[i];
}

// ---------------- W transpose + bf16 hi/lo split: W[K][256] -> Wt{hi,lo}[256][K] ----------------
template <int K>
__global__ void wsplit(const float* __restrict__ W, unsigned short* __restrict__ hi,
                       unsigned short* __restrict__ lo) {
    int t = blockIdx.x * blockDim.x + threadIdx.x;
    if (t >= K * HID_C) return;
    int k = t % K, n = t / K;
    float w = W[(long long)k * HID_C + n];
    unsigned short h = bf16_rne(w);
    unsigned short l = bf16_rne(w - bf16_to_f(h));
    hi[(long long)n * K + k] = h;
    lo[(long long)n * K + k] = l;
}

// ---------------- CSR build ----------------
__global__ void csr_count(const int* __restrict__ dst, int* __restrict__ counts) {
    int e = blockIdx.x * blockDim.x + threadIdx.x;
    if (e < N_EDGES_C) atomicAdd(&counts[dst[e]], 1);
}

#define SCAN_THREADS 1024
__global__ __launch_bounds__(SCAN_THREADS) void scan_rowptr(const int* __restrict__ counts,
                                                            int* __restrict__ rowptr) {
    __shared__ int smem[SCAN_THREADS];
    const int t = threadIdx.x;
    const int chunk = (M_NODES + SCAN_THREADS - 1) / SCAN_THREADS;
    int beg = t * chunk, end = beg + chunk;
    if (beg > M_NODES) beg = M_NODES;
    if (end > M_NODES) end = M_NODES;
    int s = 0;
    for (int i = beg; i < end; ++i) s += counts[i];
    smem[t] = s;
    __syncthreads();
    for (int off = 1; off < SCAN_THREADS; off <<= 1) {
        int add = (t >= off) ? smem[t - off] : 0;
        __syncthreads();
        smem[t] += add;
        __syncthreads();
    }
    int run = smem[t] - s;
    for (int i = beg; i < end; ++i) { rowptr[i] = run; run += counts[i]; }
    if (end == M_NODES) rowptr[M_NODES] = run;
}

__global__ void csr_fill(const int* __restrict__ src, const int* __restrict__ dst,
                         int* __restrict__ fillpos, int* __restrict__ csr_src) {
    int e = blockIdx.x * blockDim.x + threadIdx.x;
    if (e >= N_EDGES_C) return;
    int pos = atomicAdd(&fillpos[dst[e]], 1);
    csr_src[pos] = src[e];
}

// ---------------- gather aggregation: out[n] = h[n] + sum_{j->n} h[j] ----------------
template <int NQ>
__global__ __launch_bounds__(256) void gather_agg(const float* __restrict__ h,
                                                  const int* __restrict__ rowptr,
                                                  const int* __restrict__ csr_src,
                                                  float* __restrict__ out) {
    int node = blockIdx.x * (256 / NQ) + threadIdx.x / NQ;
    int q = threadIdx.x & (NQ - 1);
    if (node >= M_NODES) return;
    const float4* h4 = (const float4*)h;
    float4 acc = h4[(long long)node * NQ + q];
    int beg = rowptr[node], end = rowptr[node + 1];
    for (int e = beg; e < end; ++e) {
        int s = csr_src[e];
        float4 v = h4[(long long)s * NQ + q];
        acc.x += v.x; acc.y += v.y; acc.z += v.z; acc.w += v.w;
    }
    ((float4*)out)[(long long)node * NQ + q] = acc;
}

// ---------------- MFMA GEMM (split-bf16, ~fp32 accuracy) ----------------
// C[M,256] = A[M,K] @ W[K,256] + bias (opt relu). Wt planes are [256][K] bf16 hi/lo.
// BM=128, BN=128, 4 waves as 2x2, each wave 64x64 via 4x4 MFMA 16x16x32 tiles.
template <int K>
__global__ __launch_bounds__(256) void gemm_mfma(const float* __restrict__ A,
                                                 const unsigned short* __restrict__ BtH,
                                                 const unsigned short* __restrict__ BtL,
                                                 const float* __restrict__ bias,
                                                 float* __restrict__ Cout, int M,
                                                 int do_relu, float* __restrict__ bnsums) {
    __shared__ unsigned short AsH[128 * 40];  // pitch 40 bf16 (80B) rows
    __shared__ unsigned short AsL[128 * 40];

    const int tid = threadIdx.x;
    const int lane = tid & 63;
    const int wave = tid >> 6;
    const int wr = wave & 1, wc = wave >> 1;
    const int gm = blockIdx.y * 128;
    const int gn = blockIdx.x * 128;
    const int kb = (lane >> 4) * 8;   // k sub-block within 32
    const int l15 = lane & 15;

    floatx4 acc[4][4];
#pragma unroll
    for (int i = 0; i < 4; ++i)
#pragma unroll
        for (int j = 0; j < 4; ++j) acc[i][j] = (floatx4){0.f, 0.f, 0.f, 0.f};

    for (int k0 = 0; k0 < K; k0 += 32) {
        // stage A tile 128x32 fp32 -> bf16 hi/lo in LDS
#pragma unroll
        for (int it = 0; it < 4; ++it) {
            int r = (tid >> 3) + it * 32;
            int s = tid & 7;
            int grow = gm + r;
            if (grow >= M) grow = M - 1;
            float4 v = *(const float4*)(A + (long long)grow * K + k0 + s * 4);
            unsigned short h0 = bf16_rne(v.x), h1 = bf16_rne(v.y), h2 = bf16_rne(v.z), h3 = bf16_rne(v.w);
            unsigned short l0 = bf16_rne(v.x - bf16_to_f(h0));
            unsigned short l1 = bf16_rne(v.y - bf16_to_f(h1));
            unsigned short l2 = bf16_rne(v.z - bf16_to_f(h2));
            unsigned short l3 = bf16_rne(v.w - bf16_to_f(h3));
            uint2 hw, lw;
            hw.x = (unsigned)h0 | ((unsigned)h1 << 16);
            hw.y = (unsigned)h2 | ((unsigned)h3 << 16);
            lw.x = (unsigned)l0 | ((unsigned)l1 << 16);
            lw.y = (unsigned)l2 | ((unsigned)l3 << 16);
            *(uint2*)(&AsH[r * 40 + s * 4]) = hw;
            *(uint2*)(&AsL[r * 40 + s * 4]) = lw;
        }
        __syncthreads();

        // load fragments
        short8v afH[4], afL[4], bfH[4], bfL[4];
#pragma unroll
        for (int i = 0; i < 4; ++i) {
            int row = wr * 64 + i * 16 + l15;
            afH[i] = *(const short8v*)(&AsH[row * 40 + kb]);
            afL[i] = *(const short8v*)(&AsL[row * 40 + kb]);
        }
#pragma unroll
        for (int j = 0; j < 4; ++j) {
            int col = gn + wc * 64 + j * 16 + l15;
            bfH[j] = *(const short8v*)(BtH + (long long)col * K + k0 + kb);
            bfL[j] = *(const short8v*)(BtL + (long long)col * K + k0 + kb);
        }

#pragma unroll
        for (int i = 0; i < 4; ++i)
#pragma unroll
            for (int j = 0; j < 4; ++j) {
                acc[i][j] = __builtin_amdgcn_mfma_f32_16x16x32_bf16(afH[i], bfH[j], acc[i][j], 0, 0, 0);
                acc[i][j] = __builtin_amdgcn_mfma_f32_16x16x32_bf16(afL[i], bfH[j], acc[i][j], 0, 0, 0);
                acc[i][j] = __builtin_amdgcn_mfma_f32_16x16x32_bf16(afH[i], bfL[j], acc[i][j], 0, 0, 0);
            }
        __syncthreads();
    }

    // epilogue: bias (+relu) store; optional fused BN column sums
    const int rgrp = (lane >> 4) * 4;
#pragma unroll
    for (int j = 0; j < 4; ++j) {
        int col = gn + wc * 64 + j * 16 + l15;
        float bb = bias[col];
        float s1 = 0.f, s2 = 0.f;
#pragma unroll
        for (int i = 0; i < 4; ++i) {
            int rowb = gm + wr * 64 + i * 16 + rgrp;
#pragma unroll
            for (int r = 0; r < 4; ++r) {
                int row = rowb + r;
                if (row < M) {
                    float v = acc[i][j][r] + bb;
                    if (do_relu) v = fmaxf(v, 0.f);
                    Cout[(long long)row * HID_C + col] = v;
                    if (bnsums) { s1 += v; s2 += v * v; }
                }
            }
        }
        if (bnsums) {
            s1 += __shfl_xor(s1, 16); s1 += __shfl_xor(s1, 32);
            s2 += __shfl_xor(s2, 16); s2 += __shfl_xor(s2, 32);
            if ((lane >> 4) == 0) {
                atomicAdd(&bnsums[col], s1);
                atomicAdd(&bnsums[HID_C + col], s2);
            }
        }
    }
}

// ---------------- BatchNorm finalize/apply ----------------
__global__ void bn_finalize(const float* __restrict__ sums, const float* __restrict__ gamma,
                            const float* __restrict__ beta, float* __restrict__ ss) {
    int f = threadIdx.x;
    float mean = sums[f] * (1.0f / M_NODES);
    float var = sums[HID_C + f] * (1.0f / M_NODES) - mean * mean;
    float sc = gamma[f] * rsqrtf(var + BN_EPS_C);
    ss[f] = sc;
    ss[HID_C + f] = beta[f] - mean * sc;
}

__global__ void bn_apply_relu(const float4* __restrict__ in, const float* __restrict__ ss,
                              float4* __restrict__ out, int n4) {
    int i = blockIdx.x * blockDim.x + threadIdx.x;
    if (i >= n4) return;
    int f = (i & 63) << 2;
    float4 v = in[i];
    float4 r;
    r.x = fmaxf(v.x * ss[f + 0] + ss[HID_C + f + 0], 0.f);
    r.y = fmaxf(v.y * ss[f + 1] + ss[HID_C + f + 1], 0.f);
    r.z = fmaxf(v.z * ss[f + 2] + ss[HID_C + f + 2], 0.f);
    r.w = fmaxf(v.w * ss[f + 3] + ss[HID_C + f + 3], 0.f);
    out[i] = r;
}

// ---------------- pooling ----------------
#define POOL_ROWS 391
__global__ void pool_kernel(const float* __restrict__ h, const int* __restrict__ batch,
                            float* __restrict__ sums, int M) {
    int f = threadIdx.x;
    int r0 = blockIdx.x * POOL_ROWS;
    if (r0 >= M) return;
    int r1 = r0 + POOL_ROWS;
    if (r1 > M) r1 = M;
    int cur = batch[r0];
    float acc = 0.f;
    for (int r = r0; r < r1; ++r) {
        int g = batch[r];
        if (g != cur) {
            atomicAdd(&sums[(long long)cur * HID_C + f], acc);
            acc = 0.f;
            cur = g;
        }
        acc += h[(long long)r * HID_C + f];
    }
    atomicAdd(&sums[(long long)cur * HID_C + f], acc);
}

__device__ __forceinline__ int lower_bound_i(const int* a, int n, int v) {
    int lo = 0, hi = n;
    while (lo < hi) {
        int mid = (lo + hi) >> 1;
        if (a[mid] < v) lo = mid + 1;
        else hi = mid;
    }
    return lo;
}

__global__ void pool_finalize(const float* __restrict__ sums, const int* __restrict__ batch,
                              float* __restrict__ out) {
    int g = blockIdx.x, f = threadIdx.x;
    int lb = lower_bound_i(batch, M_NODES, g);
    int ub = lower_bound_i(batch, M_NODES, g + 1);
    float cnt = (float)(ub - lb);
    out[(long long)g * HID_C + f] = sums[(long long)g * HID_C + f] / fmaxf(cnt, 1.0f);
}

// ---------------- launch ----------------
extern "C" void kernel_launch(void* const* d_in, const int* in_sizes, int n_in,
                              void* d_out, int out_size, void* d_ws, size_t ws_size,
                              hipStream_t stream) {
    const float* x = (const float*)d_in[0];
    const int* ei = (const int*)d_in[1];
    const int* esrc = ei;
    const int* edst = ei + N_EDGES_C;
    const int* batch = (const int*)d_in[2];
    const float* W1_0 = (const float*)d_in[3];
    const float* b1_0 = (const float*)d_in[4];
    const float* W2_0 = (const float*)d_in[5];
    const float* b2_0 = (const float*)d_in[6];
    const float* g0 = (const float*)d_in[7];
    const float* be0 = (const float*)d_in[8];
    const float* W1_1 = (const float*)d_in[9];
    const float* b1_1 = (const float*)d_in[10];
    const float* W2_1 = (const float*)d_in[11];
    const float* b2_1 = (const float*)d_in[12];
    const float* g1 = (const float*)d_in[13];
    const float* be1 = (const float*)d_in[14];
    float* out = (float*)d_out;

    const long long NH = (long long)M_NODES * HID_C;
    float* B = (float*)d_ws;
    float* C = B + NH;
    float* bns = C + NH;                    // 512
    float* ss = bns + 2 * HID_C;            // 512
    int* counts = (int*)(ss + 2 * HID_C);   // 100000
    int* rowptr = counts + M_NODES;         // 100001
    int* csr_src = rowptr + (M_NODES + 1);  // 800000
    float* psum = (float*)csr_src;          // aliased (used only after last gather)
    unsigned short* wt = (unsigned short*)(csr_src + N_EDGES_C);
    unsigned short* wtAh = wt;                       // 128*256
    unsigned short* wtAl = wtAh + IN_DIM_C * HID_C;
    unsigned short* wtBh = wtAl + IN_DIM_C * HID_C;  // 256*256
    unsigned short* wtBl = wtBh + HID_C * HID_C;
    unsigned short* wtCh = wtBl + HID_C * HID_C;
    unsigned short* wtCl = wtCh + HID_C * HID_C;
    unsigned short* wtDh = wtCl + HID_C * HID_C;
    unsigned short* wtDl = wtDh + HID_C * HID_C;

    dim3 blk(256);
    dim3 ggrid(HID_C / 128, (M_NODES + 127) / 128);

    // ---- W splits ----
    wsplit<IN_DIM_C><<<(IN_DIM_C * HID_C + 255) / 256, blk, 0, stream>>>(W1_0, wtAh, wtAl);
    wsplit<HID_C><<<(HID_C * HID_C + 255) / 256, blk, 0, stream>>>(W2_0, wtBh, wtBl);
    wsplit<HID_C><<<(HID_C * HID_C + 255) / 256, blk, 0, stream>>>(W1_1, wtCh, wtCl);
    wsplit<HID_C><<<(HID_C * HID_C + 255) / 256, blk, 0, stream>>>(W2_1, wtDh, wtDl);

    // ---- CSR build ----
    zero_i<<<(M_NODES + 255) / 256, blk, 0, stream>>>(counts, M_NODES);
    csr_count<<<(N_EDGES_C + 255) / 256, blk, 0, stream>>>(edst, counts);
    scan_rowptr<<<1, SCAN_THREADS, 0, stream>>>(counts, rowptr);
    copy_i<<<(M_NODES + 255) / 256, blk, 0, stream>>>(rowptr, counts, M_NODES);
    csr_fill<<<(N_EDGES_C + 255) / 256, blk, 0, stream>>>(esrc, edst, counts, csr_src);

    // ---- Layer 0 ----
    gather_agg<IN_DIM_C / 4><<<(M_NODES * (IN_DIM_C / 4) + 255) / 256, blk, 0, stream>>>(
        x, rowptr, csr_src, B);
    gemm_mfma<IN_DIM_C><<<ggrid, blk, 0, stream>>>(B, wtAh, wtAl, b1_0, C, M_NODES, 1, nullptr);
    zero_f<<<2, blk, 0, stream>>>(bns, 2 * HID_C);
    gemm_mfma<HID_C><<<ggrid, blk, 0, stream>>>(C, wtBh, wtBl, b2_0, B, M_NODES, 0, bns);
    bn_finalize<<<1, blk, 0, stream>>>(bns, g0, be0, ss);
    bn_apply_relu<<<(int)((NH / 4 + 255) / 256), blk, 0, stream>>>((const float4*)B, ss,
                                                                   (float4*)C, (int)(NH / 4));

    // ---- Layer 1 ----
    gather_agg<HID_C / 4><<<(M_NODES * (HID_C / 4) + 255) / 256, blk, 0, stream>>>(
        C, rowptr, csr_src, B);
    gemm_mfma<HID_C><<<ggrid, blk, 0, stream>>>(B, wtCh, wtCl, b1_1, C, M_NODES, 1, nullptr);
    zero_f<<<2, blk, 0, stream>>>(bns, 2 * HID_C);
    gemm_mfma<HID_C><<<ggrid, blk, 0, stream>>>(C, wtDh, wtDl, b2_1, B, M_NODES, 0, bns);
    bn_finalize<<<1, blk, 0, stream>>>(bns, g1, be1, ss);
    bn_apply_relu<<<(int)((NH / 4 + 255) / 256), blk, 0, stream>>>((const float4*)B, ss,
                                                                   (float4*)B, (int)(NH / 4));

    // ---- Pool ----
    zero_f<<<(N_GRAPHS_C * HID_C + 255) / 256, blk, 0, stream>>>(psum, N_GRAPHS_C * HID_C);
    pool_kernel<<<256, blk, 0, stream>>>(B, batch, psum, M_NODES);
    pool_finalize<<<256, blk, 0, stream>>>(psum, batch, out);
}

// Round 4
// 1008.087 us; speedup vs baseline: 4.8788x; 1.0887x over previous
//
#include <hip/hip_runtime.h>

#define M_NODES 100000
#define N_EDGES_C 800000
#define IN_DIM_C 128
#define HID_C 256
#define N_GRAPHS_C 256
#define BN_EPS_C 1e-5f

typedef __attribute__((ext_vector_type(8))) short short8v;
typedef __attribute__((ext_vector_type(4))) float floatx4;

__device__ __forceinline__ unsigned short bf16_rne(float f) {
    union { float f; unsigned u; } x; x.f = f;
    unsigned r = x.u + 0x7FFF + ((x.u >> 16) & 1);
    return (unsigned short)(r >> 16);
}
__device__ __forceinline__ float bf16_to_f(unsigned short h) {
    union { unsigned u; float f; } x; x.u = ((unsigned)h) << 16;
    return x.f;
}

// ---------------- small helpers ----------------
__global__ void zero_f(float* __restrict__ p, int n) {
    int i = blockIdx.x * blockDim.x + threadIdx.x;
    if (i < n) p[i] = 0.f;
}
__global__ void zero_i(int* __restrict__ p, int n) {
    int i = blockIdx.x * blockDim.x + threadIdx.x;
    if (i < n) p[i] = 0;
}
__global__ void copy_i(const int* __restrict__ s, int* __restrict__ d, int n) {
    int i = blockIdx.x * blockDim.x + threadIdx.x;
    if (i < n) d[i] = s[i];
}

// ---------------- W transpose + bf16 hi/lo split: W[K][256] -> Wt{hi,lo}[256][K] ----------------
template <int K>
__global__ void wsplit(const float* __restrict__ W, unsigned short* __restrict__ hi,
                       unsigned short* __restrict__ lo) {
    int t = blockIdx.x * blockDim.x + threadIdx.x;
    if (t >= K * HID_C) return;
    int k = t % K, n = t / K;
    float w = W[(long long)k * HID_C + n];
    unsigned short h = bf16_rne(w);
    unsigned short l = bf16_rne(w - bf16_to_f(h));
    hi[(long long)n * K + k] = h;
    lo[(long long)n * K + k] = l;
}

// ---------------- CSR build ----------------
__global__ void csr_count(const int* __restrict__ dst, int* __restrict__ counts) {
    int e = blockIdx.x * blockDim.x + threadIdx.x;
    if (e < N_EDGES_C) atomicAdd(&counts[dst[e]], 1);
}

// parallel exclusive scan of counts[0..M] -> rowptr[0..M]
__global__ __launch_bounds__(256) void block_scan(const int* __restrict__ counts,
                                                  int* __restrict__ excl,
                                                  int* __restrict__ partials) {
    __shared__ int sm[256];
    int i = blockIdx.x * 256 + threadIdx.x;
    int v = (i < M_NODES) ? counts[i] : 0;
    sm[threadIdx.x] = v;
    __syncthreads();
    for (int off = 1; off < 256; off <<= 1) {
        int add = (threadIdx.x >= off) ? sm[threadIdx.x - off] : 0;
        __syncthreads();
        sm[threadIdx.x] += add;
        __syncthreads();
    }
    if (i <= M_NODES) excl[i] = sm[threadIdx.x] - v;
    if (threadIdx.x == 255) partials[blockIdx.x] = sm[255];
}

__global__ __launch_bounds__(512) void scan_partials(int* __restrict__ partials, int nb) {
    __shared__ int sm[512];
    int t = threadIdx.x;
    int v = (t < nb) ? partials[t] : 0;
    sm[t] = v;
    __syncthreads();
    for (int off = 1; off < 512; off <<= 1) {
        int add = (t >= off) ? sm[t - off] : 0;
        __syncthreads();
        sm[t] += add;
        __syncthreads();
    }
    if (t < nb) partials[t] = sm[t] - v;  // exclusive block offsets
}

__global__ void add_offsets(int* __restrict__ rowptr, const int* __restrict__ partials) {
    int i = blockIdx.x * 256 + threadIdx.x;
    if (i <= M_NODES) rowptr[i] += partials[blockIdx.x];
}

__global__ void csr_fill(const int* __restrict__ src, const int* __restrict__ dst,
                         int* __restrict__ fillpos, int* __restrict__ csr_src) {
    int e = blockIdx.x * blockDim.x + threadIdx.x;
    if (e >= N_EDGES_C) return;
    int pos = atomicAdd(&fillpos[dst[e]], 1);
    csr_src[pos] = src[e];
}

// ---------------- gather + optional BN/relu + bf16 hi/lo split ----------------
// out{H,L}[n][K] = split( proc(h[n]) + sum_{j->n} proc(h[j]) ), proc = BN? relu(v*sc+sh) : v
template <int K, bool BN>
__global__ __launch_bounds__(256) void gather_split(const float* __restrict__ h,
                                                    const int* __restrict__ rowptr,
                                                    const int* __restrict__ csr_src,
                                                    const float* __restrict__ ss,
                                                    unsigned short* __restrict__ outH,
                                                    unsigned short* __restrict__ outL) {
    constexpr int NQ = K / 4;
    int node = blockIdx.x * (256 / NQ) + threadIdx.x / NQ;
    int q = threadIdx.x & (NQ - 1);
    if (node >= M_NODES) return;
    int f = q * 4;
    float sc0 = 1.f, sc1 = 1.f, sc2 = 1.f, sc3 = 1.f;
    float sh0 = 0.f, sh1 = 0.f, sh2 = 0.f, sh3 = 0.f;
    if (BN) {
        sc0 = ss[f + 0]; sc1 = ss[f + 1]; sc2 = ss[f + 2]; sc3 = ss[f + 3];
        sh0 = ss[HID_C + f + 0]; sh1 = ss[HID_C + f + 1];
        sh2 = ss[HID_C + f + 2]; sh3 = ss[HID_C + f + 3];
    }
    const float4* h4 = (const float4*)h;

    float4 v = h4[(long long)node * NQ + q];
    float ax, ay, az, aw;
    if (BN) {
        ax = fmaxf(fmaf(v.x, sc0, sh0), 0.f);
        ay = fmaxf(fmaf(v.y, sc1, sh1), 0.f);
        az = fmaxf(fmaf(v.z, sc2, sh2), 0.f);
        aw = fmaxf(fmaf(v.w, sc3, sh3), 0.f);
    } else { ax = v.x; ay = v.y; az = v.z; aw = v.w; }

    int beg = rowptr[node], end = rowptr[node + 1];
    for (int e = beg; e < end; ++e) {
        int s = csr_src[e];
        float4 u = h4[(long long)s * NQ + q];
        if (BN) {
            ax += fmaxf(fmaf(u.x, sc0, sh0), 0.f);
            ay += fmaxf(fmaf(u.y, sc1, sh1), 0.f);
            az += fmaxf(fmaf(u.z, sc2, sh2), 0.f);
            aw += fmaxf(fmaf(u.w, sc3, sh3), 0.f);
        } else { ax += u.x; ay += u.y; az += u.z; aw += u.w; }
    }

    ushort4 hv, lv;
    hv.x = bf16_rne(ax); lv.x = bf16_rne(ax - bf16_to_f(hv.x));
    hv.y = bf16_rne(ay); lv.y = bf16_rne(ay - bf16_to_f(hv.y));
    hv.z = bf16_rne(az); lv.z = bf16_rne(az - bf16_to_f(hv.z));
    hv.w = bf16_rne(aw); lv.w = bf16_rne(aw - bf16_to_f(hv.w));
    *(ushort4*)(outH + (long long)node * K + f) = hv;
    *(ushort4*)(outL + (long long)node * K + f) = lv;
}

// ---------------- MFMA GEMM, split-bf16 operands, LDS-free ----------------
// C[M,256] = (Ah+Al)[M,K] @ (Bh+Bl)[K,256] + bias
// EPI=1: out{H,L} = split(relu(C));  EPI=0: outF = C (fp32) + fused BN column sums
template <int K, int EPI>
__global__ __launch_bounds__(256) void gemm_split(const unsigned short* __restrict__ Ah,
                                                  const unsigned short* __restrict__ Al,
                                                  const unsigned short* __restrict__ Bh,
                                                  const unsigned short* __restrict__ Bl,
                                                  const float* __restrict__ bias,
                                                  float* __restrict__ outF,
                                                  unsigned short* __restrict__ outH,
                                                  unsigned short* __restrict__ outL,
                                                  int M, float* __restrict__ bnsums) {
    const int tid = threadIdx.x;
    const int lane = tid & 63;
    const int wave = tid >> 6;
    const int wr = wave & 1, wc = wave >> 1;
    const int gm = blockIdx.y * 128;
    const int gn = blockIdx.x * 128;
    const int kb = (lane >> 4) * 8;
    const int l15 = lane & 15;

    floatx4 acc[4][4];
#pragma unroll
    for (int i = 0; i < 4; ++i)
#pragma unroll
        for (int j = 0; j < 4; ++j) acc[i][j] = (floatx4){0.f, 0.f, 0.f, 0.f};

    long long arow[4], bcol[4];
#pragma unroll
    for (int i = 0; i < 4; ++i) {
        int row = gm + wr * 64 + i * 16 + l15;
        if (row >= M) row = M - 1;
        arow[i] = (long long)row * K + kb;
    }
#pragma unroll
    for (int j = 0; j < 4; ++j)
        bcol[j] = (long long)(gn + wc * 64 + j * 16 + l15) * K + kb;

    for (int k0 = 0; k0 < K; k0 += 32) {
        short8v afH[4], afL[4], bfH[4], bfL[4];
#pragma unroll
        for (int i = 0; i < 4; ++i) {
            afH[i] = *(const short8v*)(Ah + arow[i] + k0);
            afL[i] = *(const short8v*)(Al + arow[i] + k0);
        }
#pragma unroll
        for (int j = 0; j < 4; ++j) {
            bfH[j] = *(const short8v*)(Bh + bcol[j] + k0);
            bfL[j] = *(const short8v*)(Bl + bcol[j] + k0);
        }
#pragma unroll
        for (int i = 0; i < 4; ++i)
#pragma unroll
            for (int j = 0; j < 4; ++j) {
                acc[i][j] = __builtin_amdgcn_mfma_f32_16x16x32_bf16(afH[i], bfH[j], acc[i][j], 0, 0, 0);
                acc[i][j] = __builtin_amdgcn_mfma_f32_16x16x32_bf16(afL[i], bfH[j], acc[i][j], 0, 0, 0);
                acc[i][j] = __builtin_amdgcn_mfma_f32_16x16x32_bf16(afH[i], bfL[j], acc[i][j], 0, 0, 0);
            }
    }

    const int rgrp = (lane >> 4) * 4;
#pragma unroll
    for (int j = 0; j < 4; ++j) {
        int col = gn + wc * 64 + j * 16 + l15;
        float bb = bias[col];
        float s1 = 0.f, s2 = 0.f;
#pragma unroll
        for (int i = 0; i < 4; ++i) {
            int rowb = gm + wr * 64 + i * 16 + rgrp;
#pragma unroll
            for (int r = 0; r < 4; ++r) {
                int row = rowb + r;
                if (row < M) {
                    float v = acc[i][j][r] + bb;
                    if (EPI == 1) {
                        v = fmaxf(v, 0.f);
                        unsigned short hb = bf16_rne(v);
                        outH[(long long)row * HID_C + col] = hb;
                        outL[(long long)row * HID_C + col] = bf16_rne(v - bf16_to_f(hb));
                    } else {
                        outF[(long long)row * HID_C + col] = v;
                        s1 += v; s2 += v * v;
                    }
                }
            }
        }
        if (EPI == 0) {
            s1 += __shfl_xor(s1, 16); s1 += __shfl_xor(s1, 32);
            s2 += __shfl_xor(s2, 16); s2 += __shfl_xor(s2, 32);
            if ((lane >> 4) == 0) {
                atomicAdd(&bnsums[col], s1);
                atomicAdd(&bnsums[HID_C + col], s2);
            }
        }
    }
}

// ---------------- BatchNorm finalize ----------------
__global__ void bn_finalize(const float* __restrict__ sums, const float* __restrict__ gamma,
                            const float* __restrict__ beta, float* __restrict__ ss) {
    int f = threadIdx.x;
    float mean = sums[f] * (1.0f / M_NODES);
    float var = sums[HID_C + f] * (1.0f / M_NODES) - mean * mean;
    float sc = gamma[f] * rsqrtf(var + BN_EPS_C);
    ss[f] = sc;
    ss[HID_C + f] = beta[f] - mean * sc;
}

// ---------------- pooling with fused BN+relu ----------------
#define POOL_ROWS 391
__global__ void pool_bn(const float* __restrict__ h, const float* __restrict__ ss,
                        const int* __restrict__ batch, float* __restrict__ sums, int M) {
    int f = threadIdx.x;
    float sc = ss[f], sh = ss[HID_C + f];
    int r0 = blockIdx.x * POOL_ROWS;
    if (r0 >= M) return;
    int r1 = r0 + POOL_ROWS;
    if (r1 > M) r1 = M;
    int cur = batch[r0];
    float acc = 0.f;
    for (int r = r0; r < r1; ++r) {
        int g = batch[r];
        if (g != cur) {
            atomicAdd(&sums[(long long)cur * HID_C + f], acc);
            acc = 0.f;
            cur = g;
        }
        acc += fmaxf(fmaf(h[(long long)r * HID_C + f], sc, sh), 0.f);
    }
    atomicAdd(&sums[(long long)cur * HID_C + f], acc);
}

__device__ __forceinline__ int lower_bound_i(const int* a, int n, int v) {
    int lo = 0, hi = n;
    while (lo < hi) {
        int mid = (lo + hi) >> 1;
        if (a[mid] < v) lo = mid + 1;
        else hi = mid;
    }
    return lo;
}

__global__ void pool_finalize(const float* __restrict__ sums, const int* __restrict__ batch,
                              float* __restrict__ out) {
    int g = blockIdx.x, f = threadIdx.x;
    int lb = lower_bound_i(batch, M_NODES, g);
    int ub = lower_bound_i(batch, M_NODES, g + 1);
    float cnt = (float)(ub - lb);
    out[(long long)g * HID_C + f] = sums[(long long)g * HID_C + f] / fmaxf(cnt, 1.0f);
}

// ---------------- launch ----------------
extern "C" void kernel_launch(void* const* d_in, const int* in_sizes, int n_in,
                              void* d_out, int out_size, void* d_ws, size_t ws_size,
                              hipStream_t stream) {
    const float* x = (const float*)d_in[0];
    const int* ei = (const int*)d_in[1];
    const int* esrc = ei;
    const int* edst = ei + N_EDGES_C;
    const int* batch = (const int*)d_in[2];
    const float* W1_0 = (const float*)d_in[3];
    const float* b1_0 = (const float*)d_in[4];
    const float* W2_0 = (const float*)d_in[5];
    const float* b2_0 = (const float*)d_in[6];
    const float* g0 = (const float*)d_in[7];
    const float* be0 = (const float*)d_in[8];
    const float* W1_1 = (const float*)d_in[9];
    const float* b1_1 = (const float*)d_in[10];
    const float* W2_1 = (const float*)d_in[11];
    const float* b2_1 = (const float*)d_in[12];
    const float* g1 = (const float*)d_in[13];
    const float* be1 = (const float*)d_in[14];
    float* out = (float*)d_out;

    const long long NF = (long long)M_NODES * HID_C;  // 25.6M elems
    float* R1 = (float*)d_ws;                         // 102.4 MB region
    float* R2 = R1 + NF;                              // 102.4 MB region
    float* bns = R2 + NF;                             // 512
    float* ss0 = bns + 2 * HID_C;                     // 512
    float* ss1 = ss0 + 2 * HID_C;                     // 512
    float* psum = ss1 + 2 * HID_C;                    // 65536
    int* counts = (int*)(psum + N_GRAPHS_C * HID_C);  // 100352
    int* partials = counts + 100352;                  // 512
    int* rowptr = partials + 512;                     // 100004
    int* csr_src = rowptr + 100004;                   // 800000
    unsigned short* wp = (unsigned short*)(csr_src + N_EDGES_C);
    unsigned short* wAh = wp;
    unsigned short* wAl = wAh + IN_DIM_C * HID_C;
    unsigned short* wBh = wAl + IN_DIM_C * HID_C;
    unsigned short* wBl = wBh + HID_C * HID_C;
    unsigned short* wCh = wBl + HID_C * HID_C;
    unsigned short* wCl = wCh + HID_C * HID_C;
    unsigned short* wDh = wCl + HID_C * HID_C;
    unsigned short* wDl = wDh + HID_C * HID_C;

    // typed ping-pong views
    unsigned short* Ah0 = (unsigned short*)R1;            // 100k x 128
    unsigned short* Al0 = Ah0 + (long long)M_NODES * IN_DIM_C;
    unsigned short* Hh = (unsigned short*)R2;             // 100k x 256
    unsigned short* Hl = Hh + NF;
    float* P0 = R1;
    unsigned short* Ah1 = (unsigned short*)R2;
    unsigned short* Al1 = Ah1 + NF;
    unsigned short* Hh2 = (unsigned short*)R1;
    unsigned short* Hl2 = Hh2 + NF;
    float* P1 = R2;

    dim3 blk(256);
    dim3 ggrid(HID_C / 128, (M_NODES + 127) / 128);

    // ---- W splits ----
    wsplit<IN_DIM_C><<<(IN_DIM_C * HID_C + 255) / 256, blk, 0, stream>>>(W1_0, wAh, wAl);
    wsplit<HID_C><<<(HID_C * HID_C + 255) / 256, blk, 0, stream>>>(W2_0, wBh, wBl);
    wsplit<HID_C><<<(HID_C * HID_C + 255) / 256, blk, 0, stream>>>(W1_1, wCh, wCl);
    wsplit<HID_C><<<(HID_C * HID_C + 255) / 256, blk, 0, stream>>>(W2_1, wDh, wDl);

    // ---- CSR build ----
    zero_i<<<(M_NODES + 255) / 256, blk, 0, stream>>>(counts, M_NODES);
    csr_count<<<(N_EDGES_C + 255) / 256, blk, 0, stream>>>(edst, counts);
    block_scan<<<392, blk, 0, stream>>>(counts, rowptr, partials);
    scan_partials<<<1, 512, 0, stream>>>(partials, 392);
    add_offsets<<<392, blk, 0, stream>>>(rowptr, partials);
    copy_i<<<(M_NODES + 255) / 256, blk, 0, stream>>>(rowptr, counts, M_NODES);
    csr_fill<<<(N_EDGES_C + 255) / 256, blk, 0, stream>>>(esrc, edst, counts, csr_src);

    // ---- Layer 0 ----
    gather_split<IN_DIM_C, false><<<M_NODES / 8, blk, 0, stream>>>(x, rowptr, csr_src,
                                                                   nullptr, Ah0, Al0);
    gemm_split<IN_DIM_C, 1><<<ggrid, blk, 0, stream>>>(Ah0, Al0, wAh, wAl, b1_0,
                                                       nullptr, Hh, Hl, M_NODES, nullptr);
    zero_f<<<2, blk, 0, stream>>>(bns, 2 * HID_C);
    gemm_split<HID_C, 0><<<ggrid, blk, 0, stream>>>(Hh, Hl, wBh, wBl, b2_0,
                                                    P0, nullptr, nullptr, M_NODES, bns);
    bn_finalize<<<1, blk, 0, stream>>>(bns, g0, be0, ss0);

    // ---- Layer 1 ----
    gather_split<HID_C, true><<<M_NODES / 4, blk, 0, stream>>>(P0, rowptr, csr_src,
                                                               ss0, Ah1, Al1);
    gemm_split<HID_C, 1><<<ggrid, blk, 0, stream>>>(Ah1, Al1, wCh, wCl, b1_1,
                                                    nullptr, Hh2, Hl2, M_NODES, nullptr);
    zero_f<<<2, blk, 0, stream>>>(bns, 2 * HID_C);
    gemm_split<HID_C, 0><<<ggrid, blk, 0, stream>>>(Hh2, Hl2, wDh, wDl, b2_1,
                                                    P1, nullptr, nullptr, M_NODES, bns);
    bn_finalize<<<1, blk, 0, stream>>>(bns, g1, be1, ss1);

    // ---- Pool (fused BN+relu) ----
    zero_f<<<(N_GRAPHS_C * HID_C + 255) / 256, blk, 0, stream>>>(psum, N_GRAPHS_C * HID_C);
    pool_bn<<<256, blk, 0, stream>>>(P1, ss1, batch, psum, M_NODES);
    pool_finalize<<<256, blk, 0, stream>>>(psum, batch, out);
}

// Round 5
// 930.107 us; speedup vs baseline: 5.2878x; 1.0838x over previous
//
#include <hip/hip_runtime.h>

#define M_NODES 100000
#define N_EDGES_C 800000
#define IN_DIM_C 128
#define HID_C 256
#define N_GRAPHS_C 256
#define BN_EPS_C 1e-5f

typedef __attribute__((ext_vector_type(8))) short short8v;
typedef __attribute__((ext_vector_type(4))) float floatx4;

__device__ __forceinline__ unsigned short bf16_rne(float f) {
    union { float f; unsigned u; } x; x.f = f;
    unsigned r = x.u + 0x7FFF + ((x.u >> 16) & 1);
    return (unsigned short)(r >> 16);
}
__device__ __forceinline__ float bf16_to_f(unsigned short h) {
    union { unsigned u; float f; } x; x.u = ((unsigned)h) << 16;
    return x.f;
}

// ---------------- small helpers ----------------
__global__ void zero_f(float* __restrict__ p, int n) {
    int i = blockIdx.x * blockDim.x + threadIdx.x;
    if (i < n) p[i] = 0.f;
}
__global__ void zero_i(int* __restrict__ p, int n) {
    int i = blockIdx.x * blockDim.x + threadIdx.x;
    if (i < n) p[i] = 0;
}
__global__ void copy_i(const int* __restrict__ s, int* __restrict__ d, int n) {
    int i = blockIdx.x * blockDim.x + threadIdx.x;
    if (i < n) d[i] = s[i];
}

// ---------------- W transpose + bf16 hi/lo split: W[K][256] -> Wt{hi,lo}[256][K] ----------------
template <int K>
__global__ void wsplit(const float* __restrict__ W, unsigned short* __restrict__ hi,
                       unsigned short* __restrict__ lo) {
    int t = blockIdx.x * blockDim.x + threadIdx.x;
    if (t >= K * HID_C) return;
    int k = t % K, n = t / K;
    float w = W[(long long)k * HID_C + n];
    unsigned short h = bf16_rne(w);
    unsigned short l = bf16_rne(w - bf16_to_f(h));
    hi[(long long)n * K + k] = h;
    lo[(long long)n * K + k] = l;
}

// ---------------- CSR build ----------------
__global__ void csr_count(const int* __restrict__ dst, int* __restrict__ counts) {
    int e = blockIdx.x * blockDim.x + threadIdx.x;
    if (e < N_EDGES_C) atomicAdd(&counts[dst[e]], 1);
}

__global__ __launch_bounds__(256) void block_scan(const int* __restrict__ counts,
                                                  int* __restrict__ excl,
                                                  int* __restrict__ partials) {
    __shared__ int sm[256];
    int i = blockIdx.x * 256 + threadIdx.x;
    int v = (i < M_NODES) ? counts[i] : 0;
    sm[threadIdx.x] = v;
    __syncthreads();
    for (int off = 1; off < 256; off <<= 1) {
        int add = (threadIdx.x >= off) ? sm[threadIdx.x - off] : 0;
        __syncthreads();
        sm[threadIdx.x] += add;
        __syncthreads();
    }
    if (i <= M_NODES) excl[i] = sm[threadIdx.x] - v;
    if (threadIdx.x == 255) partials[blockIdx.x] = sm[255];
}

__global__ __launch_bounds__(512) void scan_partials(int* __restrict__ partials, int nb) {
    __shared__ int sm[512];
    int t = threadIdx.x;
    int v = (t < nb) ? partials[t] : 0;
    sm[t] = v;
    __syncthreads();
    for (int off = 1; off < 512; off <<= 1) {
        int add = (t >= off) ? sm[t - off] : 0;
        __syncthreads();
        sm[t] += add;
        __syncthreads();
    }
    if (t < nb) partials[t] = sm[t] - v;
}

__global__ void add_offsets(int* __restrict__ rowptr, const int* __restrict__ partials) {
    int i = blockIdx.x * 256 + threadIdx.x;
    if (i <= M_NODES) rowptr[i] += partials[blockIdx.x];
}

__global__ void csr_fill(const int* __restrict__ src, const int* __restrict__ dst,
                         int* __restrict__ fillpos, int* __restrict__ csr_src) {
    int e = blockIdx.x * blockDim.x + threadIdx.x;
    if (e >= N_EDGES_C) return;
    int pos = atomicAdd(&fillpos[dst[e]], 1);
    csr_src[pos] = src[e];
}

// ---------------- gather + optional BN/relu + bf16 hi/lo split ----------------
template <int K, bool BN>
__global__ __launch_bounds__(256) void gather_split(const float* __restrict__ h,
                                                    const int* __restrict__ rowptr,
                                                    const int* __restrict__ csr_src,
                                                    const float* __restrict__ ss,
                                                    unsigned short* __restrict__ outH,
                                                    unsigned short* __restrict__ outL) {
    constexpr int NQ = K / 4;
    int node = blockIdx.x * (256 / NQ) + threadIdx.x / NQ;
    int q = threadIdx.x & (NQ - 1);
    if (node >= M_NODES) return;
    int f = q * 4;
    float sc0 = 1.f, sc1 = 1.f, sc2 = 1.f, sc3 = 1.f;
    float sh0 = 0.f, sh1 = 0.f, sh2 = 0.f, sh3 = 0.f;
    if (BN) {
        sc0 = ss[f + 0]; sc1 = ss[f + 1]; sc2 = ss[f + 2]; sc3 = ss[f + 3];
        sh0 = ss[HID_C + f + 0]; sh1 = ss[HID_C + f + 1];
        sh2 = ss[HID_C + f + 2]; sh3 = ss[HID_C + f + 3];
    }
    const float4* h4 = (const float4*)h;

    float4 v = h4[(long long)node * NQ + q];
    float ax, ay, az, aw;
    if (BN) {
        ax = fmaxf(fmaf(v.x, sc0, sh0), 0.f);
        ay = fmaxf(fmaf(v.y, sc1, sh1), 0.f);
        az = fmaxf(fmaf(v.z, sc2, sh2), 0.f);
        aw = fmaxf(fmaf(v.w, sc3, sh3), 0.f);
    } else { ax = v.x; ay = v.y; az = v.z; aw = v.w; }

    int beg = rowptr[node], end = rowptr[node + 1];
    for (int e = beg; e < end; ++e) {
        int s = csr_src[e];
        float4 u = h4[(long long)s * NQ + q];
        if (BN) {
            ax += fmaxf(fmaf(u.x, sc0, sh0), 0.f);
            ay += fmaxf(fmaf(u.y, sc1, sh1), 0.f);
            az += fmaxf(fmaf(u.z, sc2, sh2), 0.f);
            aw += fmaxf(fmaf(u.w, sc3, sh3), 0.f);
        } else { ax += u.x; ay += u.y; az += u.z; aw += u.w; }
    }

    ushort4 hv, lv;
    hv.x = bf16_rne(ax); lv.x = bf16_rne(ax - bf16_to_f(hv.x));
    hv.y = bf16_rne(ay); lv.y = bf16_rne(ay - bf16_to_f(hv.y));
    hv.z = bf16_rne(az); lv.z = bf16_rne(az - bf16_to_f(hv.z));
    hv.w = bf16_rne(aw); lv.w = bf16_rne(aw - bf16_to_f(hv.w));
    *(ushort4*)(outH + (long long)node * K + f) = hv;
    *(ushort4*)(outL + (long long)node * K + f) = lv;
}

// ---------------- MFMA GEMM, split-bf16 operands, LDS-transposed coalesced epilogue ----------------
// C[M,256] = (Ah+Al)[M,K] @ (Bh+Bl)[K,256] + bias
// EPI=1: out{H,L} = split(relu(C));  EPI=0: outF = C (fp32) + fused BN column sums
template <int K, int EPI>
__global__ __launch_bounds__(256) void gemm_split(const unsigned short* __restrict__ Ah,
                                                  const unsigned short* __restrict__ Al,
                                                  const unsigned short* __restrict__ Bh,
                                                  const unsigned short* __restrict__ Bl,
                                                  const float* __restrict__ bias,
                                                  float* __restrict__ outF,
                                                  unsigned short* __restrict__ outH,
                                                  unsigned short* __restrict__ outL,
                                                  int M, float* __restrict__ bnsums) {
    __shared__ unsigned int sm[128 * 65];  // 33.3 KB transpose staging

    const int tid = threadIdx.x;
    const int lane = tid & 63;
    const int wave = tid >> 6;
    const int wr = wave & 1, wc = wave >> 1;
    const int gm = blockIdx.y * 128;
    const int gn = blockIdx.x * 128;
    const int kb = (lane >> 4) * 8;
    const int l15 = lane & 15;

    floatx4 acc[4][4];
#pragma unroll
    for (int i = 0; i < 4; ++i)
#pragma unroll
        for (int j = 0; j < 4; ++j) acc[i][j] = (floatx4){0.f, 0.f, 0.f, 0.f};

    long long arow[4], bcol[4];
#pragma unroll
    for (int i = 0; i < 4; ++i) {
        int row = gm + wr * 64 + i * 16 + l15;
        if (row >= M) row = M - 1;
        arow[i] = (long long)row * K + kb;
    }
#pragma unroll
    for (int j = 0; j < 4; ++j)
        bcol[j] = (long long)(gn + wc * 64 + j * 16 + l15) * K + kb;

    for (int k0 = 0; k0 < K; k0 += 32) {
        short8v afH[4], afL[4], bfH[4], bfL[4];
#pragma unroll
        for (int i = 0; i < 4; ++i) {
            afH[i] = *(const short8v*)(Ah + arow[i] + k0);
            afL[i] = *(const short8v*)(Al + arow[i] + k0);
        }
#pragma unroll
        for (int j = 0; j < 4; ++j) {
            bfH[j] = *(const short8v*)(Bh + bcol[j] + k0);
            bfL[j] = *(const short8v*)(Bl + bcol[j] + k0);
        }
#pragma unroll
        for (int i = 0; i < 4; ++i)
#pragma unroll
            for (int j = 0; j < 4; ++j) {
                acc[i][j] = __builtin_amdgcn_mfma_f32_16x16x32_bf16(afH[i], bfH[j], acc[i][j], 0, 0, 0);
                acc[i][j] = __builtin_amdgcn_mfma_f32_16x16x32_bf16(afL[i], bfH[j], acc[i][j], 0, 0, 0);
                acc[i][j] = __builtin_amdgcn_mfma_f32_16x16x32_bf16(afH[i], bfL[j], acc[i][j], 0, 0, 0);
            }
    }

    const int rgrp = (lane >> 4) * 4;

    // fused BN column sums (pre-BN h, EPI==0)
    if (EPI == 0) {
#pragma unroll
        for (int j = 0; j < 4; ++j) {
            int col = gn + wc * 64 + j * 16 + l15;
            float bb = bias[col];
            float s1 = 0.f, s2 = 0.f;
#pragma unroll
            for (int i = 0; i < 4; ++i) {
                int rowb = gm + wr * 64 + i * 16 + rgrp;
#pragma unroll
                for (int r = 0; r < 4; ++r) {
                    if (rowb + r < M) {
                        float v = acc[i][j][r] + bb;
                        s1 += v; s2 += v * v;
                    }
                }
            }
            s1 += __shfl_xor(s1, 16); s1 += __shfl_xor(s1, 32);
            s2 += __shfl_xor(s2, 16); s2 += __shfl_xor(s2, 32);
            if ((lane >> 4) == 0) {
                atomicAdd(&bnsums[col], s1);
                atomicAdd(&bnsums[HID_C + col], s2);
            }
        }
    }

    // phased LDS-transpose epilogue: 2 phases x (128 rows x 64 cols)
#pragma unroll
    for (int p = 0; p < 2; ++p) {
        __syncthreads();
        if (wc == p) {
#pragma unroll
            for (int j = 0; j < 4; ++j) {
                int col = gn + p * 64 + j * 16 + l15;
                float bb = bias[col];
#pragma unroll
                for (int i = 0; i < 4; ++i) {
                    int lrow = wr * 64 + i * 16 + rgrp;
#pragma unroll
                    for (int r = 0; r < 4; ++r) {
                        float v = acc[i][j][r] + bb;
                        unsigned u;
                        if (EPI == 1) {
                            v = fmaxf(v, 0.f);
                            unsigned short hb = bf16_rne(v);
                            unsigned short lb = bf16_rne(v - bf16_to_f(hb));
                            u = (unsigned)hb | ((unsigned)lb << 16);
                        } else {
                            u = __float_as_uint(v);
                        }
                        sm[(lrow + r) * 65 + j * 16 + l15] = u;
                    }
                }
            }
        }
        __syncthreads();
        // coalesced store: 128 rows x 32 col-pairs
#pragma unroll
        for (int it = 0; it < 16; ++it) {
            int idx = it * 256 + tid;
            int row = idx >> 5;
            int cp = idx & 31;
            int grow = gm + row;
            if (grow < M) {
                unsigned u0 = sm[row * 65 + cp * 2];
                unsigned u1 = sm[row * 65 + cp * 2 + 1];
                long long base = (long long)grow * HID_C + gn + p * 64 + cp * 2;
                if (EPI == 1) {
                    ushort2 hv, lv;
                    hv.x = (unsigned short)(u0 & 0xffff);
                    hv.y = (unsigned short)(u1 & 0xffff);
                    lv.x = (unsigned short)(u0 >> 16);
                    lv.y = (unsigned short)(u1 >> 16);
                    *(ushort2*)(outH + base) = hv;
                    *(ushort2*)(outL + base) = lv;
                } else {
                    float2 fv;
                    fv.x = __uint_as_float(u0);
                    fv.y = __uint_as_float(u1);
                    *(float2*)(outF + base) = fv;
                }
            }
        }
    }
}

// ---------------- BatchNorm finalize ----------------
__global__ void bn_finalize(const float* __restrict__ sums, const float* __restrict__ gamma,
                            const float* __restrict__ beta, float* __restrict__ ss) {
    int f = threadIdx.x;
    float mean = sums[f] * (1.0f / M_NODES);
    float var = sums[HID_C + f] * (1.0f / M_NODES) - mean * mean;
    float sc = gamma[f] * rsqrtf(var + BN_EPS_C);
    ss[f] = sc;
    ss[HID_C + f] = beta[f] - mean * sc;
}

// ---------------- pooling with fused BN+relu ----------------
#define POOL_ROWS 391
__global__ void pool_bn(const float* __restrict__ h, const float* __restrict__ ss,
                        const int* __restrict__ batch, float* __restrict__ sums, int M) {
    int f = threadIdx.x;
    float sc = ss[f], sh = ss[HID_C + f];
    int r0 = blockIdx.x * POOL_ROWS;
    if (r0 >= M) return;
    int r1 = r0 + POOL_ROWS;
    if (r1 > M) r1 = M;
    int cur = batch[r0];
    float acc = 0.f;
    for (int r = r0; r < r1; ++r) {
        int g = batch[r];
        if (g != cur) {
            atomicAdd(&sums[(long long)cur * HID_C + f], acc);
            acc = 0.f;
            cur = g;
        }
        acc += fmaxf(fmaf(h[(long long)r * HID_C + f], sc, sh), 0.f);
    }
    atomicAdd(&sums[(long long)cur * HID_C + f], acc);
}

__device__ __forceinline__ int lower_bound_i(const int* a, int n, int v) {
    int lo = 0, hi = n;
    while (lo < hi) {
        int mid = (lo + hi) >> 1;
        if (a[mid] < v) lo = mid + 1;
        else hi = mid;
    }
    return lo;
}

__global__ void pool_finalize(const float* __restrict__ sums, const int* __restrict__ batch,
                              float* __restrict__ out) {
    int g = blockIdx.x, f = threadIdx.x;
    int lb = lower_bound_i(batch, M_NODES, g);
    int ub = lower_bound_i(batch, M_NODES, g + 1);
    float cnt = (float)(ub - lb);
    out[(long long)g * HID_C + f] = sums[(long long)g * HID_C + f] / fmaxf(cnt, 1.0f);
}

// ---------------- launch ----------------
extern "C" void kernel_launch(void* const* d_in, const int* in_sizes, int n_in,
                              void* d_out, int out_size, void* d_ws, size_t ws_size,
                              hipStream_t stream) {
    const float* x = (const float*)d_in[0];
    const int* ei = (const int*)d_in[1];
    const int* esrc = ei;
    const int* edst = ei + N_EDGES_C;
    const int* batch = (const int*)d_in[2];
    const float* W1_0 = (const float*)d_in[3];
    const float* b1_0 = (const float*)d_in[4];
    const float* W2_0 = (const float*)d_in[5];
    const float* b2_0 = (const float*)d_in[6];
    const float* g0 = (const float*)d_in[7];
    const float* be0 = (const float*)d_in[8];
    const float* W1_1 = (const float*)d_in[9];
    const float* b1_1 = (const float*)d_in[10];
    const float* W2_1 = (const float*)d_in[11];
    const float* b2_1 = (const float*)d_in[12];
    const float* g1 = (const float*)d_in[13];
    const float* be1 = (const float*)d_in[14];
    float* out = (float*)d_out;

    const long long NF = (long long)M_NODES * HID_C;
    float* R1 = (float*)d_ws;
    float* R2 = R1 + NF;
    float* bns = R2 + NF;
    float* ss0 = bns + 2 * HID_C;
    float* ss1 = ss0 + 2 * HID_C;
    float* psum = ss1 + 2 * HID_C;
    int* counts = (int*)(psum + N_GRAPHS_C * HID_C);
    int* partials = counts + 100352;
    int* rowptr = partials + 512;
    int* csr_src = rowptr + 100004;
    unsigned short* wp = (unsigned short*)(csr_src + N_EDGES_C);
    unsigned short* wAh = wp;
    unsigned short* wAl = wAh + IN_DIM_C * HID_C;
    unsigned short* wBh = wAl + IN_DIM_C * HID_C;
    unsigned short* wBl = wBh + HID_C * HID_C;
    unsigned short* wCh = wBl + HID_C * HID_C;
    unsigned short* wCl = wCh + HID_C * HID_C;
    unsigned short* wDh = wCl + HID_C * HID_C;
    unsigned short* wDl = wDh + HID_C * HID_C;

    unsigned short* Ah0 = (unsigned short*)R1;
    unsigned short* Al0 = Ah0 + (long long)M_NODES * IN_DIM_C;
    unsigned short* Hh = (unsigned short*)R2;
    unsigned short* Hl = Hh + NF;
    float* P0 = R1;
    unsigned short* Ah1 = (unsigned short*)R2;
    unsigned short* Al1 = Ah1 + NF;
    unsigned short* Hh2 = (unsigned short*)R1;
    unsigned short* Hl2 = Hh2 + NF;
    float* P1 = R2;

    dim3 blk(256);
    dim3 ggrid(HID_C / 128, (M_NODES + 127) / 128);

    // ---- W splits ----
    wsplit<IN_DIM_C><<<(IN_DIM_C * HID_C + 255) / 256, blk, 0, stream>>>(W1_0, wAh, wAl);
    wsplit<HID_C><<<(HID_C * HID_C + 255) / 256, blk, 0, stream>>>(W2_0, wBh, wBl);
    wsplit<HID_C><<<(HID_C * HID_C + 255) / 256, blk, 0, stream>>>(W1_1, wCh, wCl);
    wsplit<HID_C><<<(HID_C * HID_C + 255) / 256, blk, 0, stream>>>(W2_1, wDh, wDl);

    // ---- CSR build ----
    zero_i<<<(M_NODES + 255) / 256, blk, 0, stream>>>(counts, M_NODES);
    csr_count<<<(N_EDGES_C + 255) / 256, blk, 0, stream>>>(edst, counts);
    block_scan<<<392, blk, 0, stream>>>(counts, rowptr, partials);
    scan_partials<<<1, 512, 0, stream>>>(partials, 392);
    add_offsets<<<392, blk, 0, stream>>>(rowptr, partials);
    copy_i<<<(M_NODES + 255) / 256, blk, 0, stream>>>(rowptr, counts, M_NODES);
    csr_fill<<<(N_EDGES_C + 255) / 256, blk, 0, stream>>>(esrc, edst, counts, csr_src);

    // ---- Layer 0 ----
    gather_split<IN_DIM_C, false><<<M_NODES / 8, blk, 0, stream>>>(x, rowptr, csr_src,
                                                                   nullptr, Ah0, Al0);
    gemm_split<IN_DIM_C, 1><<<ggrid, blk, 0, stream>>>(Ah0, Al0, wAh, wAl, b1_0,
                                                       nullptr, Hh, Hl, M_NODES, nullptr);
    zero_f<<<2, blk, 0, stream>>>(bns, 2 * HID_C);
    gemm_split<HID_C, 0><<<ggrid, blk, 0, stream>>>(Hh, Hl, wBh, wBl, b2_0,
                                                    P0, nullptr, nullptr, M_NODES, bns);
    bn_finalize<<<1, blk, 0, stream>>>(bns, g0, be0, ss0);

    // ---- Layer 1 ----
    gather_split<HID_C, true><<<M_NODES / 4, blk, 0, stream>>>(P0, rowptr, csr_src,
                                                               ss0, Ah1, Al1);
    gemm_split<HID_C, 1><<<ggrid, blk, 0, stream>>>(Ah1, Al1, wCh, wCl, b1_1,
                                                    nullptr, Hh2, Hl2, M_NODES, nullptr);
    zero_f<<<2, blk, 0, stream>>>(bns, 2 * HID_C);
    gemm_split<HID_C, 0><<<ggrid, blk, 0, stream>>>(Hh2, Hl2, wDh, wDl, b2_1,
                                                    P1, nullptr, nullptr, M_NODES, bns);
    bn_finalize<<<1, blk, 0, stream>>>(bns, g1, be1, ss1);

    // ---- Pool (fused BN+relu) ----
    zero_f<<<(N_GRAPHS_C * HID_C + 255) / 256, blk, 0, stream>>>(psum, N_GRAPHS_C * HID_C);
    pool_bn<<<256, blk, 0, stream>>>(P1, ss1, batch, psum, M_NODES);
    pool_finalize<<<256, blk, 0, stream>>>(psum, batch, out);
}

// Round 6
// 752.429 us; speedup vs baseline: 6.5365x; 1.2361x over previous
//
#include <hip/hip_runtime.h>

#define M_NODES 100000
#define N_EDGES_C 800000
#define IN_DIM_C 128
#define HID_C 256
#define N_GRAPHS_C 256
#define BN_EPS_C 1e-5f

typedef __attribute__((ext_vector_type(8))) short short8v;
typedef __attribute__((ext_vector_type(4))) float floatx4;

__device__ __forceinline__ unsigned short bf16_rne(float f) {
    union { float f; unsigned u; } x; x.f = f;
    unsigned r = x.u + 0x7FFF + ((x.u >> 16) & 1);
    return (unsigned short)(r >> 16);
}
__device__ __forceinline__ float bf16_to_f(unsigned short h) {
    union { unsigned u; float f; } x; x.u = ((unsigned)h) << 16;
    return x.f;
}

// ---------------- small helpers ----------------
__global__ void zero_f(float* __restrict__ p, int n) {
    int i = blockIdx.x * blockDim.x + threadIdx.x;
    if (i < n) p[i] = 0.f;
}
__global__ void zero_i(int* __restrict__ p, int n) {
    int i = blockIdx.x * blockDim.x + threadIdx.x;
    if (i < n) p[i] = 0;
}
__global__ void copy_i(const int* __restrict__ s, int* __restrict__ d, int n) {
    int i = blockIdx.x * blockDim.x + threadIdx.x;
    if (i < n) d[i] = s[i];
}

// ---------------- W transpose + bf16 hi/lo split: W[K][256] -> Wt{hi,lo}[256][K] ----------------
template <int K>
__global__ void wsplit(const float* __restrict__ W, unsigned short* __restrict__ hi,
                       unsigned short* __restrict__ lo) {
    int t = blockIdx.x * blockDim.x + threadIdx.x;
    if (t >= K * HID_C) return;
    int k = t % K, n = t / K;
    float w = W[(long long)k * HID_C + n];
    unsigned short h = bf16_rne(w);
    unsigned short l = bf16_rne(w - bf16_to_f(h));
    hi[(long long)n * K + k] = h;
    lo[(long long)n * K + k] = l;
}

// ---------------- CSR build ----------------
__global__ void csr_count(const int* __restrict__ dst, int* __restrict__ counts) {
    int e = blockIdx.x * blockDim.x + threadIdx.x;
    if (e < N_EDGES_C) atomicAdd(&counts[dst[e]], 1);
}

__global__ __launch_bounds__(256) void block_scan(const int* __restrict__ counts,
                                                  int* __restrict__ excl,
                                                  int* __restrict__ partials) {
    __shared__ int sm[256];
    int i = blockIdx.x * 256 + threadIdx.x;
    int v = (i < M_NODES) ? counts[i] : 0;
    sm[threadIdx.x] = v;
    __syncthreads();
    for (int off = 1; off < 256; off <<= 1) {
        int add = (threadIdx.x >= off) ? sm[threadIdx.x - off] : 0;
        __syncthreads();
        sm[threadIdx.x] += add;
        __syncthreads();
    }
    if (i <= M_NODES) excl[i] = sm[threadIdx.x] - v;
    if (threadIdx.x == 255) partials[blockIdx.x] = sm[255];
}

__global__ __launch_bounds__(512) void scan_partials(int* __restrict__ partials, int nb) {
    __shared__ int sm[512];
    int t = threadIdx.x;
    int v = (t < nb) ? partials[t] : 0;
    sm[t] = v;
    __syncthreads();
    for (int off = 1; off < 512; off <<= 1) {
        int add = (t >= off) ? sm[t - off] : 0;
        __syncthreads();
        sm[t] += add;
        __syncthreads();
    }
    if (t < nb) partials[t] = sm[t] - v;
}

__global__ void add_offsets(int* __restrict__ rowptr, const int* __restrict__ partials) {
    int i = blockIdx.x * 256 + threadIdx.x;
    if (i <= M_NODES) rowptr[i] += partials[blockIdx.x];
}

__global__ void csr_fill(const int* __restrict__ src, const int* __restrict__ dst,
                         int* __restrict__ fillpos, int* __restrict__ csr_src) {
    int e = blockIdx.x * blockDim.x + threadIdx.x;
    if (e >= N_EDGES_C) return;
    int pos = atomicAdd(&fillpos[dst[e]], 1);
    csr_src[pos] = src[e];
}

// ---------------- gather + optional BN/relu -> single bf16 plane ----------------
template <int K, bool BN>
__global__ __launch_bounds__(256) void gather_bf16(const float* __restrict__ h,
                                                   const int* __restrict__ rowptr,
                                                   const int* __restrict__ csr_src,
                                                   const float* __restrict__ ss,
                                                   unsigned short* __restrict__ outH) {
    constexpr int NQ = K / 4;
    int node = blockIdx.x * (256 / NQ) + threadIdx.x / NQ;
    int q = threadIdx.x & (NQ - 1);
    if (node >= M_NODES) return;
    int f = q * 4;
    float sc0 = 1.f, sc1 = 1.f, sc2 = 1.f, sc3 = 1.f;
    float sh0 = 0.f, sh1 = 0.f, sh2 = 0.f, sh3 = 0.f;
    if (BN) {
        sc0 = ss[f + 0]; sc1 = ss[f + 1]; sc2 = ss[f + 2]; sc3 = ss[f + 3];
        sh0 = ss[HID_C + f + 0]; sh1 = ss[HID_C + f + 1];
        sh2 = ss[HID_C + f + 2]; sh3 = ss[HID_C + f + 3];
    }
    const float4* h4 = (const float4*)h;

    float4 v = h4[(long long)node * NQ + q];
    float ax, ay, az, aw;
    if (BN) {
        ax = fmaxf(fmaf(v.x, sc0, sh0), 0.f);
        ay = fmaxf(fmaf(v.y, sc1, sh1), 0.f);
        az = fmaxf(fmaf(v.z, sc2, sh2), 0.f);
        aw = fmaxf(fmaf(v.w, sc3, sh3), 0.f);
    } else { ax = v.x; ay = v.y; az = v.z; aw = v.w; }

    int beg = rowptr[node], end = rowptr[node + 1];
    for (int e = beg; e < end; ++e) {
        int s = csr_src[e];
        float4 u = h4[(long long)s * NQ + q];
        if (BN) {
            ax += fmaxf(fmaf(u.x, sc0, sh0), 0.f);
            ay += fmaxf(fmaf(u.y, sc1, sh1), 0.f);
            az += fmaxf(fmaf(u.z, sc2, sh2), 0.f);
            aw += fmaxf(fmaf(u.w, sc3, sh3), 0.f);
        } else { ax += u.x; ay += u.y; az += u.z; aw += u.w; }
    }

    ushort4 hv;
    hv.x = bf16_rne(ax);
    hv.y = bf16_rne(ay);
    hv.z = bf16_rne(az);
    hv.w = bf16_rne(aw);
    *(ushort4*)(outH + (long long)node * K + f) = hv;
}

// ---------------- MFMA GEMM, 2-term split (A bf16, W hi+lo), coalesced epilogue ----------------
// C[M,256] = A[M,K] @ (Bh+Bl)[K,256] + bias
// EPI=1: outH = bf16(relu(C));  EPI=0: outF = C (fp32) + fused BN column sums
template <int K, int EPI>
__global__ __launch_bounds__(256, 2) void gemm_2t(const unsigned short* __restrict__ A,
                                                  const unsigned short* __restrict__ Bh,
                                                  const unsigned short* __restrict__ Bl,
                                                  const float* __restrict__ bias,
                                                  float* __restrict__ outF,
                                                  unsigned short* __restrict__ outH,
                                                  int M, float* __restrict__ bnsums) {
    constexpr int SMEMU = (EPI == 1) ? (128 * 36) : (128 * 65);
    __shared__ unsigned smem[SMEMU];

    const int tid = threadIdx.x;
    const int lane = tid & 63;
    const int wave = tid >> 6;
    const int wr = wave & 1, wc = wave >> 1;
    const int gm = blockIdx.y * 128;
    const int gn = blockIdx.x * 128;
    const int kb = (lane >> 4) * 8;
    const int l15 = lane & 15;

    floatx4 acc[4][4];
#pragma unroll
    for (int i = 0; i < 4; ++i)
#pragma unroll
        for (int j = 0; j < 4; ++j) acc[i][j] = (floatx4){0.f, 0.f, 0.f, 0.f};

    long long arow[4], bcol[4];
#pragma unroll
    for (int i = 0; i < 4; ++i) {
        int row = gm + wr * 64 + i * 16 + l15;
        if (row >= M) row = M - 1;
        arow[i] = (long long)row * K + kb;
    }
#pragma unroll
    for (int j = 0; j < 4; ++j)
        bcol[j] = (long long)(gn + wc * 64 + j * 16 + l15) * K + kb;

#pragma unroll
    for (int k0 = 0; k0 < K; k0 += 32) {
        short8v af[4], bh[4], bl[4];
#pragma unroll
        for (int i = 0; i < 4; ++i)
            af[i] = *(const short8v*)(A + arow[i] + k0);
#pragma unroll
        for (int j = 0; j < 4; ++j) {
            bh[j] = *(const short8v*)(Bh + bcol[j] + k0);
            bl[j] = *(const short8v*)(Bl + bcol[j] + k0);
        }
#pragma unroll
        for (int i = 0; i < 4; ++i)
#pragma unroll
            for (int j = 0; j < 4; ++j) {
                acc[i][j] = __builtin_amdgcn_mfma_f32_16x16x32_bf16(af[i], bh[j], acc[i][j], 0, 0, 0);
                acc[i][j] = __builtin_amdgcn_mfma_f32_16x16x32_bf16(af[i], bl[j], acc[i][j], 0, 0, 0);
            }
    }

    const int rgrp = (lane >> 4) * 4;

    if (EPI == 0) {
        // fused BN column sums on pre-BN activations
#pragma unroll
        for (int j = 0; j < 4; ++j) {
            int col = gn + wc * 64 + j * 16 + l15;
            float bb = bias[col];
            float s1 = 0.f, s2 = 0.f;
#pragma unroll
            for (int i = 0; i < 4; ++i) {
                int rowb = gm + wr * 64 + i * 16 + rgrp;
#pragma unroll
                for (int r = 0; r < 4; ++r) {
                    if (rowb + r < M) {
                        float v = acc[i][j][r] + bb;
                        s1 += v; s2 += v * v;
                    }
                }
            }
            s1 += __shfl_xor(s1, 16); s1 += __shfl_xor(s1, 32);
            s2 += __shfl_xor(s2, 16); s2 += __shfl_xor(s2, 32);
            if ((lane >> 4) == 0) {
                atomicAdd(&bnsums[col], s1);
                atomicAdd(&bnsums[HID_C + col], s2);
            }
        }

        // fp32 LDS-transpose epilogue (pitch 65 words)
#pragma unroll
        for (int p = 0; p < 2; ++p) {
            __syncthreads();
            if (wc == p) {
#pragma unroll
                for (int j = 0; j < 4; ++j) {
                    int col = gn + p * 64 + j * 16 + l15;
                    float bb = bias[col];
#pragma unroll
                    for (int i = 0; i < 4; ++i) {
                        int lrow = wr * 64 + i * 16 + rgrp;
#pragma unroll
                        for (int r = 0; r < 4; ++r)
                            smem[(lrow + r) * 65 + j * 16 + l15] =
                                __float_as_uint(acc[i][j][r] + bb);
                    }
                }
            }
            __syncthreads();
#pragma unroll
            for (int it = 0; it < 16; ++it) {
                int idx = it * 256 + tid;
                int row = idx >> 5;
                int cp = idx & 31;
                int grow = gm + row;
                if (grow < M) {
                    float2 fv;
                    fv.x = __uint_as_float(smem[row * 65 + cp * 2]);
                    fv.y = __uint_as_float(smem[row * 65 + cp * 2 + 1]);
                    *(float2*)(outF + (long long)grow * HID_C + gn + p * 64 + cp * 2) = fv;
                }
            }
        }
    } else {
        // bf16 LDS-transpose epilogue (u16 pitch 72)
        unsigned short* smu = (unsigned short*)smem;
#pragma unroll
        for (int p = 0; p < 2; ++p) {
            __syncthreads();
            if (wc == p) {
#pragma unroll
                for (int j = 0; j < 4; ++j) {
                    int col = gn + p * 64 + j * 16 + l15;
                    float bb = bias[col];
#pragma unroll
                    for (int i = 0; i < 4; ++i) {
                        int lrow = wr * 64 + i * 16 + rgrp;
#pragma unroll
                        for (int r = 0; r < 4; ++r) {
                            float v = fmaxf(acc[i][j][r] + bb, 0.f);
                            smu[(lrow + r) * 72 + j * 16 + l15] = bf16_rne(v);
                        }
                    }
                }
            }
            __syncthreads();
#pragma unroll
            for (int it = 0; it < 8; ++it) {
                int idx = it * 256 + tid;
                int row = idx >> 4;
                int q = idx & 15;
                int grow = gm + row;
                if (grow < M)
                    *(ushort4*)(outH + (long long)grow * HID_C + gn + p * 64 + q * 4) =
                        *(const ushort4*)&smu[row * 72 + q * 4];
            }
        }
    }
}

// ---------------- BatchNorm finalize ----------------
__global__ void bn_finalize(const float* __restrict__ sums, const float* __restrict__ gamma,
                            const float* __restrict__ beta, float* __restrict__ ss) {
    int f = threadIdx.x;
    float mean = sums[f] * (1.0f / M_NODES);
    float var = sums[HID_C + f] * (1.0f / M_NODES) - mean * mean;
    float sc = gamma[f] * rsqrtf(var + BN_EPS_C);
    ss[f] = sc;
    ss[HID_C + f] = beta[f] - mean * sc;
}

// ---------------- pooling with fused BN+relu ----------------
#define POOL_ROWS 391
__global__ void pool_bn(const float* __restrict__ h, const float* __restrict__ ss,
                        const int* __restrict__ batch, float* __restrict__ sums, int M) {
    int f = threadIdx.x;
    float sc = ss[f], sh = ss[HID_C + f];
    int r0 = blockIdx.x * POOL_ROWS;
    if (r0 >= M) return;
    int r1 = r0 + POOL_ROWS;
    if (r1 > M) r1 = M;
    int cur = batch[r0];
    float acc = 0.f;
    for (int r = r0; r < r1; ++r) {
        int g = batch[r];
        if (g != cur) {
            atomicAdd(&sums[(long long)cur * HID_C + f], acc);
            acc = 0.f;
            cur = g;
        }
        acc += fmaxf(fmaf(h[(long long)r * HID_C + f], sc, sh), 0.f);
    }
    atomicAdd(&sums[(long long)cur * HID_C + f], acc);
}

__device__ __forceinline__ int lower_bound_i(const int* a, int n, int v) {
    int lo = 0, hi = n;
    while (lo < hi) {
        int mid = (lo + hi) >> 1;
        if (a[mid] < v) lo = mid + 1;
        else hi = mid;
    }
    return lo;
}

__global__ void pool_finalize(const float* __restrict__ sums, const int* __restrict__ batch,
                              float* __restrict__ out) {
    int g = blockIdx.x, f = threadIdx.x;
    int lb = lower_bound_i(batch, M_NODES, g);
    int ub = lower_bound_i(batch, M_NODES, g + 1);
    float cnt = (float)(ub - lb);
    out[(long long)g * HID_C + f] = sums[(long long)g * HID_C + f] / fmaxf(cnt, 1.0f);
}

// ---------------- launch ----------------
extern "C" void kernel_launch(void* const* d_in, const int* in_sizes, int n_in,
                              void* d_out, int out_size, void* d_ws, size_t ws_size,
                              hipStream_t stream) {
    const float* x = (const float*)d_in[0];
    const int* ei = (const int*)d_in[1];
    const int* esrc = ei;
    const int* edst = ei + N_EDGES_C;
    const int* batch = (const int*)d_in[2];
    const float* W1_0 = (const float*)d_in[3];
    const float* b1_0 = (const float*)d_in[4];
    const float* W2_0 = (const float*)d_in[5];
    const float* b2_0 = (const float*)d_in[6];
    const float* g0 = (const float*)d_in[7];
    const float* be0 = (const float*)d_in[8];
    const float* W1_1 = (const float*)d_in[9];
    const float* b1_1 = (const float*)d_in[10];
    const float* W2_1 = (const float*)d_in[11];
    const float* b2_1 = (const float*)d_in[12];
    const float* g1 = (const float*)d_in[13];
    const float* be1 = (const float*)d_in[14];
    float* out = (float*)d_out;

    const long long NF = (long long)M_NODES * HID_C;
    float* R1 = (float*)d_ws;
    float* R2 = R1 + NF;
    float* bns = R2 + NF;
    float* ss0 = bns + 2 * HID_C;
    float* ss1 = ss0 + 2 * HID_C;
    float* psum = ss1 + 2 * HID_C;
    int* counts = (int*)(psum + N_GRAPHS_C * HID_C);
    int* partials = counts + 100352;
    int* rowptr = partials + 512;
    int* csr_src = rowptr + 100004;
    unsigned short* wp = (unsigned short*)(csr_src + N_EDGES_C);
    unsigned short* wAh = wp;
    unsigned short* wAl = wAh + IN_DIM_C * HID_C;
    unsigned short* wBh = wAl + IN_DIM_C * HID_C;
    unsigned short* wBl = wBh + HID_C * HID_C;
    unsigned short* wCh = wBl + HID_C * HID_C;
    unsigned short* wCl = wCh + HID_C * HID_C;
    unsigned short* wDh = wCl + HID_C * HID_C;
    unsigned short* wDl = wDh + HID_C * HID_C;

    // ping-pong typed views
    unsigned short* A0 = (unsigned short*)R1;   // 100k x 128 bf16
    unsigned short* H = (unsigned short*)R2;    // 100k x 256 bf16
    float* P0 = R1;                             // 100k x 256 fp32
    unsigned short* A1 = (unsigned short*)R2;   // 100k x 256 bf16
    unsigned short* H2 = (unsigned short*)R1;   // 100k x 256 bf16
    float* P1 = R2;                             // 100k x 256 fp32

    dim3 blk(256);
    dim3 ggrid(HID_C / 128, (M_NODES + 127) / 128);

    // ---- W splits ----
    wsplit<IN_DIM_C><<<(IN_DIM_C * HID_C + 255) / 256, blk, 0, stream>>>(W1_0, wAh, wAl);
    wsplit<HID_C><<<(HID_C * HID_C + 255) / 256, blk, 0, stream>>>(W2_0, wBh, wBl);
    wsplit<HID_C><<<(HID_C * HID_C + 255) / 256, blk, 0, stream>>>(W1_1, wCh, wCl);
    wsplit<HID_C><<<(HID_C * HID_C + 255) / 256, blk, 0, stream>>>(W2_1, wDh, wDl);

    // ---- CSR build ----
    zero_i<<<(M_NODES + 255) / 256, blk, 0, stream>>>(counts, M_NODES);
    csr_count<<<(N_EDGES_C + 255) / 256, blk, 0, stream>>>(edst, counts);
    block_scan<<<392, blk, 0, stream>>>(counts, rowptr, partials);
    scan_partials<<<1, 512, 0, stream>>>(partials, 392);
    add_offsets<<<392, blk, 0, stream>>>(rowptr, partials);
    copy_i<<<(M_NODES + 255) / 256, blk, 0, stream>>>(rowptr, counts, M_NODES);
    csr_fill<<<(N_EDGES_C + 255) / 256, blk, 0, stream>>>(esrc, edst, counts, csr_src);

    // ---- Layer 0 ----
    gather_bf16<IN_DIM_C, false><<<M_NODES / 8, blk, 0, stream>>>(x, rowptr, csr_src,
                                                                  nullptr, A0);
    gemm_2t<IN_DIM_C, 1><<<ggrid, blk, 0, stream>>>(A0, wAh, wAl, b1_0,
                                                    nullptr, H, M_NODES, nullptr);
    zero_f<<<2, blk, 0, stream>>>(bns, 2 * HID_C);
    gemm_2t<HID_C, 0><<<ggrid, blk, 0, stream>>>(H, wBh, wBl, b2_0,
                                                 P0, nullptr, M_NODES, bns);
    bn_finalize<<<1, blk, 0, stream>>>(bns, g0, be0, ss0);

    // ---- Layer 1 ----
    gather_bf16<HID_C, true><<<M_NODES / 4, blk, 0, stream>>>(P0, rowptr, csr_src,
                                                              ss0, A1);
    gemm_2t<HID_C, 1><<<ggrid, blk, 0, stream>>>(A1, wCh, wCl, b1_1,
                                                 nullptr, H2, M_NODES, nullptr);
    zero_f<<<2, blk, 0, stream>>>(bns, 2 * HID_C);
    gemm_2t<HID_C, 0><<<ggrid, blk, 0, stream>>>(H2, wDh, wDl, b2_1,
                                                 P1, nullptr, M_NODES, bns);
    bn_finalize<<<1, blk, 0, stream>>>(bns, g1, be1, ss1);

    // ---- Pool (fused BN+relu) ----
    zero_f<<<(N_GRAPHS_C * HID_C + 255) / 256, blk, 0, stream>>>(psum, N_GRAPHS_C * HID_C);
    pool_bn<<<256, blk, 0, stream>>>(P1, ss1, batch, psum, M_NODES);
    pool_finalize<<<256, blk, 0, stream>>>(psum, batch, out);
}

// Round 7
// 619.004 us; speedup vs baseline: 7.9454x; 1.2155x over previous
//
#include <hip/hip_runtime.h>

#define M_NODES 100000
#define N_EDGES_C 800000
#define IN_DIM_C 128
#define HID_C 256
#define N_GRAPHS_C 256
#define BN_EPS_C 1e-5f

typedef __attribute__((ext_vector_type(8))) short short8v;
typedef __attribute__((ext_vector_type(4))) float floatx4;

__device__ __forceinline__ unsigned short bf16_rne(float f) {
    union { float f; unsigned u; } x; x.f = f;
    unsigned r = x.u + 0x7FFF + ((x.u >> 16) & 1);
    return (unsigned short)(r >> 16);
}
__device__ __forceinline__ float bf16_to_f(unsigned short h) {
    union { unsigned u; float f; } x; x.u = ((unsigned)h) << 16;
    return x.f;
}
__device__ __forceinline__ float bf16lo_f(unsigned u) {  // bits 0-15
    union { unsigned u; float f; } x; x.u = u << 16;
    return x.f;
}
__device__ __forceinline__ float bf16hi_f(unsigned u) {  // bits 16-31
    union { unsigned u; float f; } x; x.u = u & 0xffff0000u;
    return x.f;
}

// ---------------- small helpers ----------------
__global__ void zero_f(float* __restrict__ p, int n) {
    int i = blockIdx.x * blockDim.x + threadIdx.x;
    if (i < n) p[i] = 0.f;
}
__global__ void zero_i(int* __restrict__ p, int n) {
    int i = blockIdx.x * blockDim.x + threadIdx.x;
    if (i < n) p[i] = 0;
}
__global__ void copy_i(const int* __restrict__ s, int* __restrict__ d, int n) {
    int i = blockIdx.x * blockDim.x + threadIdx.x;
    if (i < n) d[i] = s[i];
}
// fp32 -> bf16 elementwise (float4 -> ushort4)
__global__ void f2b(const float4* __restrict__ in, ushort4* __restrict__ out, int n4) {
    int i = blockIdx.x * blockDim.x + threadIdx.x;
    if (i >= n4) return;
    float4 v = in[i];
    ushort4 o;
    o.x = bf16_rne(v.x); o.y = bf16_rne(v.y); o.z = bf16_rne(v.z); o.w = bf16_rne(v.w);
    out[i] = o;
}

// ---------------- W transpose + bf16 hi/lo split ----------------
template <int K>
__global__ void wsplit(const float* __restrict__ W, unsigned short* __restrict__ hi,
                       unsigned short* __restrict__ lo) {
    int t = blockIdx.x * blockDim.x + threadIdx.x;
    if (t >= K * HID_C) return;
    int k = t % K, n = t / K;
    float w = W[(long long)k * HID_C + n];
    unsigned short h = bf16_rne(w);
    unsigned short l = bf16_rne(w - bf16_to_f(h));
    hi[(long long)n * K + k] = h;
    lo[(long long)n * K + k] = l;
}

// ---------------- CSR build ----------------
__global__ void csr_count(const int* __restrict__ dst, int* __restrict__ counts) {
    int e = blockIdx.x * blockDim.x + threadIdx.x;
    if (e < N_EDGES_C) atomicAdd(&counts[dst[e]], 1);
}

__global__ __launch_bounds__(256) void block_scan(const int* __restrict__ counts,
                                                  int* __restrict__ excl,
                                                  int* __restrict__ partials) {
    __shared__ int sm[256];
    int i = blockIdx.x * 256 + threadIdx.x;
    int v = (i < M_NODES) ? counts[i] : 0;
    sm[threadIdx.x] = v;
    __syncthreads();
    for (int off = 1; off < 256; off <<= 1) {
        int add = (threadIdx.x >= off) ? sm[threadIdx.x - off] : 0;
        __syncthreads();
        sm[threadIdx.x] += add;
        __syncthreads();
    }
    if (i <= M_NODES) excl[i] = sm[threadIdx.x] - v;
    if (threadIdx.x == 255) partials[blockIdx.x] = sm[255];
}

__global__ __launch_bounds__(512) void scan_partials(int* __restrict__ partials, int nb) {
    __shared__ int sm[512];
    int t = threadIdx.x;
    int v = (t < nb) ? partials[t] : 0;
    sm[t] = v;
    __syncthreads();
    for (int off = 1; off < 512; off <<= 1) {
        int add = (t >= off) ? sm[t - off] : 0;
        __syncthreads();
        sm[t] += add;
        __syncthreads();
    }
    if (t < nb) partials[t] = sm[t] - v;
}

__global__ void add_offsets(int* __restrict__ rowptr, const int* __restrict__ partials) {
    int i = blockIdx.x * 256 + threadIdx.x;
    if (i <= M_NODES) rowptr[i] += partials[blockIdx.x];
}

__global__ void csr_fill(const int* __restrict__ src, const int* __restrict__ dst,
                         int* __restrict__ fillpos, int* __restrict__ csr_src) {
    int e = blockIdx.x * blockDim.x + threadIdx.x;
    if (e >= N_EDGES_C) return;
    int pos = atomicAdd(&fillpos[dst[e]], 1);
    csr_src[pos] = src[e];
}

// ---------------- gather (bf16 in) + optional BN/relu -> bf16 out ----------------
// NE = K/8 threads per node, 8 features (one uint4) each.
template <int K, bool BN>
__global__ __launch_bounds__(256) void gather_b16(const unsigned short* __restrict__ h,
                                                  const int* __restrict__ rowptr,
                                                  const int* __restrict__ csr_src,
                                                  const float* __restrict__ ss,
                                                  unsigned short* __restrict__ outH) {
    constexpr int NE = K / 8;
    int node = blockIdx.x * (256 / NE) + threadIdx.x / NE;
    int q = threadIdx.x & (NE - 1);
    if (node >= M_NODES) return;
    int f = q * 8;
    float sc[8], sh[8];
    if (BN) {
#pragma unroll
        for (int i = 0; i < 8; ++i) { sc[i] = ss[f + i]; sh[i] = ss[HID_C + f + i]; }
    }
    float a[8];
    {
        uint4 u = *(const uint4*)(h + (long long)node * K + f);
        float t0 = bf16lo_f(u.x), t1 = bf16hi_f(u.x), t2 = bf16lo_f(u.y), t3 = bf16hi_f(u.y);
        float t4 = bf16lo_f(u.z), t5 = bf16hi_f(u.z), t6 = bf16lo_f(u.w), t7 = bf16hi_f(u.w);
        float t[8] = {t0, t1, t2, t3, t4, t5, t6, t7};
#pragma unroll
        for (int i = 0; i < 8; ++i)
            a[i] = BN ? fmaxf(fmaf(t[i], sc[i], sh[i]), 0.f) : t[i];
    }
    int beg = rowptr[node], end = rowptr[node + 1];
    for (int e = beg; e < end; ++e) {
        long long s = csr_src[e];
        uint4 u = *(const uint4*)(h + s * K + f);
        float t[8] = {bf16lo_f(u.x), bf16hi_f(u.x), bf16lo_f(u.y), bf16hi_f(u.y),
                      bf16lo_f(u.z), bf16hi_f(u.z), bf16lo_f(u.w), bf16hi_f(u.w)};
#pragma unroll
        for (int i = 0; i < 8; ++i)
            a[i] += BN ? fmaxf(fmaf(t[i], sc[i], sh[i]), 0.f) : t[i];
    }
    uint4 o;
    o.x = (unsigned)bf16_rne(a[0]) | ((unsigned)bf16_rne(a[1]) << 16);
    o.y = (unsigned)bf16_rne(a[2]) | ((unsigned)bf16_rne(a[3]) << 16);
    o.z = (unsigned)bf16_rne(a[4]) | ((unsigned)bf16_rne(a[5]) << 16);
    o.w = (unsigned)bf16_rne(a[6]) | ((unsigned)bf16_rne(a[7]) << 16);
    *(uint4*)(outH + (long long)node * K + f) = o;
}

// ---------------- MFMA GEMM, 2-term split (A bf16, W hi+lo), bf16 out ----------------
// EPI=1: outH = bf16(relu(C));  EPI=0: outH = bf16(C) + fused BN column sums (fp32 exact)
template <int K, int EPI>
__global__ __launch_bounds__(256, 4) void gemm_2t(const unsigned short* __restrict__ A,
                                                  const unsigned short* __restrict__ Bh,
                                                  const unsigned short* __restrict__ Bl,
                                                  const float* __restrict__ bias,
                                                  unsigned short* __restrict__ outH,
                                                  int M, float* __restrict__ bnsums) {
    __shared__ unsigned short smu[128 * 68];  // 17 KB, pitch 68 u16

    const int tid = threadIdx.x;
    const int lane = tid & 63;
    const int wave = tid >> 6;
    const int wr = wave & 1, wc = wave >> 1;
    const int gm = blockIdx.y * 128;
    const int gn = blockIdx.x * 128;
    const int kb = (lane >> 4) * 8;
    const int l15 = lane & 15;

    floatx4 acc[4][4];
#pragma unroll
    for (int i = 0; i < 4; ++i)
#pragma unroll
        for (int j = 0; j < 4; ++j) acc[i][j] = (floatx4){0.f, 0.f, 0.f, 0.f};

    long long arow[4], bcol[4];
#pragma unroll
    for (int i = 0; i < 4; ++i) {
        int row = gm + wr * 64 + i * 16 + l15;
        if (row >= M) row = M - 1;
        arow[i] = (long long)row * K + kb;
    }
#pragma unroll
    for (int j = 0; j < 4; ++j)
        bcol[j] = (long long)(gn + wc * 64 + j * 16 + l15) * K + kb;

#pragma unroll
    for (int k0 = 0; k0 < K; k0 += 32) {
        short8v af[4], bh[4], bl[4];
#pragma unroll
        for (int i = 0; i < 4; ++i)
            af[i] = *(const short8v*)(A + arow[i] + k0);
#pragma unroll
        for (int j = 0; j < 4; ++j) {
            bh[j] = *(const short8v*)(Bh + bcol[j] + k0);
            bl[j] = *(const short8v*)(Bl + bcol[j] + k0);
        }
#pragma unroll
        for (int i = 0; i < 4; ++i)
#pragma unroll
            for (int j = 0; j < 4; ++j) {
                acc[i][j] = __builtin_amdgcn_mfma_f32_16x16x32_bf16(af[i], bh[j], acc[i][j], 0, 0, 0);
                acc[i][j] = __builtin_amdgcn_mfma_f32_16x16x32_bf16(af[i], bl[j], acc[i][j], 0, 0, 0);
            }
    }

    const int rgrp = (lane >> 4) * 4;

    if (EPI == 0) {
        // fused BN column sums on exact fp32 pre-BN activations
#pragma unroll
        for (int j = 0; j < 4; ++j) {
            int col = gn + wc * 64 + j * 16 + l15;
            float bb = bias[col];
            float s1 = 0.f, s2 = 0.f;
#pragma unroll
            for (int i = 0; i < 4; ++i) {
                int rowb = gm + wr * 64 + i * 16 + rgrp;
#pragma unroll
                for (int r = 0; r < 4; ++r) {
                    if (rowb + r < M) {
                        float v = acc[i][j][r] + bb;
                        s1 += v; s2 += v * v;
                    }
                }
            }
            s1 += __shfl_xor(s1, 16); s1 += __shfl_xor(s1, 32);
            s2 += __shfl_xor(s2, 16); s2 += __shfl_xor(s2, 32);
            if ((lane >> 4) == 0) {
                atomicAdd(&bnsums[col], s1);
                atomicAdd(&bnsums[HID_C + col], s2);
            }
        }
    }

    // bf16 LDS-transpose epilogue
#pragma unroll
    for (int p = 0; p < 2; ++p) {
        __syncthreads();
        if (wc == p) {
#pragma unroll
            for (int j = 0; j < 4; ++j) {
                int col = gn + p * 64 + j * 16 + l15;
                float bb = bias[col];
#pragma unroll
                for (int i = 0; i < 4; ++i) {
                    int lrow = wr * 64 + i * 16 + rgrp;
#pragma unroll
                    for (int r = 0; r < 4; ++r) {
                        float v = acc[i][j][r] + bb;
                        if (EPI == 1) v = fmaxf(v, 0.f);
                        smu[(lrow + r) * 68 + j * 16 + l15] = bf16_rne(v);
                    }
                }
            }
        }
        __syncthreads();
#pragma unroll
        for (int it = 0; it < 8; ++it) {
            int idx = it * 256 + tid;
            int row = idx >> 4;
            int q = idx & 15;
            int grow = gm + row;
            if (grow < M)
                *(ushort4*)(outH + (long long)grow * HID_C + gn + p * 64 + q * 4) =
                    *(const ushort4*)&smu[row * 68 + q * 4];
        }
    }
}

// ---------------- BatchNorm finalize ----------------
__global__ void bn_finalize(const float* __restrict__ sums, const float* __restrict__ gamma,
                            const float* __restrict__ beta, float* __restrict__ ss) {
    int f = threadIdx.x;
    float mean = sums[f] * (1.0f / M_NODES);
    float var = sums[HID_C + f] * (1.0f / M_NODES) - mean * mean;
    float sc = gamma[f] * rsqrtf(var + BN_EPS_C);
    ss[f] = sc;
    ss[HID_C + f] = beta[f] - mean * sc;
}

// ---------------- pooling (bf16 in, fused BN+relu), 4096 blocks ----------------
#define POOL_BLOCKS 4096
#define POOL_RPB 25
__global__ void pool_bn(const unsigned short* __restrict__ h, const float* __restrict__ ss,
                        const int* __restrict__ batch, float* __restrict__ sums, int M) {
    int f = threadIdx.x;
    float sc = ss[f], sh = ss[HID_C + f];
    int r0 = blockIdx.x * POOL_RPB;
    if (r0 >= M) return;
    int r1 = r0 + POOL_RPB;
    if (r1 > M) r1 = M;
    int cur = batch[r0];
    float acc = 0.f;
    for (int r = r0; r < r1; ++r) {
        int g = batch[r];
        if (g != cur) {
            atomicAdd(&sums[(long long)cur * HID_C + f], acc);
            acc = 0.f;
            cur = g;
        }
        float v = bf16_to_f(h[(long long)r * HID_C + f]);
        acc += fmaxf(fmaf(v, sc, sh), 0.f);
    }
    atomicAdd(&sums[(long long)cur * HID_C + f], acc);
}

__device__ __forceinline__ int lower_bound_i(const int* a, int n, int v) {
    int lo = 0, hi = n;
    while (lo < hi) {
        int mid = (lo + hi) >> 1;
        if (a[mid] < v) lo = mid + 1;
        else hi = mid;
    }
    return lo;
}

__global__ void pool_finalize(const float* __restrict__ sums, const int* __restrict__ batch,
                              float* __restrict__ out) {
    int g = blockIdx.x, f = threadIdx.x;
    int lb = lower_bound_i(batch, M_NODES, g);
    int ub = lower_bound_i(batch, M_NODES, g + 1);
    float cnt = (float)(ub - lb);
    out[(long long)g * HID_C + f] = sums[(long long)g * HID_C + f] / fmaxf(cnt, 1.0f);
}

// ---------------- launch ----------------
extern "C" void kernel_launch(void* const* d_in, const int* in_sizes, int n_in,
                              void* d_out, int out_size, void* d_ws, size_t ws_size,
                              hipStream_t stream) {
    const float* x = (const float*)d_in[0];
    const int* ei = (const int*)d_in[1];
    const int* esrc = ei;
    const int* edst = ei + N_EDGES_C;
    const int* batch = (const int*)d_in[2];
    const float* W1_0 = (const float*)d_in[3];
    const float* b1_0 = (const float*)d_in[4];
    const float* W2_0 = (const float*)d_in[5];
    const float* b2_0 = (const float*)d_in[6];
    const float* g0 = (const float*)d_in[7];
    const float* be0 = (const float*)d_in[8];
    const float* W1_1 = (const float*)d_in[9];
    const float* b1_1 = (const float*)d_in[10];
    const float* W2_1 = (const float*)d_in[11];
    const float* b2_1 = (const float*)d_in[12];
    const float* g1 = (const float*)d_in[13];
    const float* be1 = (const float*)d_in[14];
    float* out = (float*)d_out;

    const long long NF = (long long)M_NODES * HID_C;      // 25.6M
    const long long NI = (long long)M_NODES * IN_DIM_C;   // 12.8M
    unsigned short* U = (unsigned short*)d_ws;
    // region plan (u16 elems):
    unsigned short* X16 = U;            // NI   (later H2 region base)
    unsigned short* A0 = U + NI;        // NI
    unsigned short* H  = U + 2 * NI;    // NF   (later A1)
    unsigned short* Hb0 = H + NF;       // NF   (later Hb1)
    unsigned short* A1 = H;
    unsigned short* H2 = U;             // NF (overwrites X16+A0)
    unsigned short* Hb1 = Hb0;
    float* fbase = (float*)(Hb0 + NF);
    float* bns = fbase;                          // 512
    float* ss0 = bns + 2 * HID_C;                // 512
    float* ss1 = ss0 + 2 * HID_C;                // 512
    float* psum = ss1 + 2 * HID_C;               // 65536
    int* counts = (int*)(psum + N_GRAPHS_C * HID_C);  // 100352
    int* partials = counts + 100352;             // 512
    int* rowptr = partials + 512;                // 100004
    int* csr_src = rowptr + 100004;              // 800000
    unsigned short* wp = (unsigned short*)(csr_src + N_EDGES_C);
    unsigned short* wAh = wp;
    unsigned short* wAl = wAh + IN_DIM_C * HID_C;
    unsigned short* wBh = wAl + IN_DIM_C * HID_C;
    unsigned short* wBl = wBh + HID_C * HID_C;
    unsigned short* wCh = wBl + HID_C * HID_C;
    unsigned short* wCl = wCh + HID_C * HID_C;
    unsigned short* wDh = wCl + HID_C * HID_C;
    unsigned short* wDl = wDh + HID_C * HID_C;

    dim3 blk(256);
    dim3 ggrid(HID_C / 128, (M_NODES + 127) / 128);

    // ---- W splits ----
    wsplit<IN_DIM_C><<<(IN_DIM_C * HID_C + 255) / 256, blk, 0, stream>>>(W1_0, wAh, wAl);
    wsplit<HID_C><<<(HID_C * HID_C + 255) / 256, blk, 0, stream>>>(W2_0, wBh, wBl);
    wsplit<HID_C><<<(HID_C * HID_C + 255) / 256, blk, 0, stream>>>(W1_1, wCh, wCl);
    wsplit<HID_C><<<(HID_C * HID_C + 255) / 256, blk, 0, stream>>>(W2_1, wDh, wDl);

    // ---- CSR build ----
    zero_i<<<(M_NODES + 255) / 256, blk, 0, stream>>>(counts, M_NODES);
    csr_count<<<(N_EDGES_C + 255) / 256, blk, 0, stream>>>(edst, counts);
    block_scan<<<392, blk, 0, stream>>>(counts, rowptr, partials);
    scan_partials<<<1, 512, 0, stream>>>(partials, 392);
    add_offsets<<<392, blk, 0, stream>>>(rowptr, partials);
    copy_i<<<(M_NODES + 255) / 256, blk, 0, stream>>>(rowptr, counts, M_NODES);
    csr_fill<<<(N_EDGES_C + 255) / 256, blk, 0, stream>>>(esrc, edst, counts, csr_src);

    // ---- x -> bf16 ----
    f2b<<<(int)((NI / 4 + 255) / 256), blk, 0, stream>>>((const float4*)x, (ushort4*)X16,
                                                         (int)(NI / 4));

    // ---- Layer 0 ----
    gather_b16<IN_DIM_C, false><<<(M_NODES + 15) / 16, blk, 0, stream>>>(X16, rowptr, csr_src,
                                                                         nullptr, A0);
    gemm_2t<IN_DIM_C, 1><<<ggrid, blk, 0, stream>>>(A0, wAh, wAl, b1_0, H, M_NODES, nullptr);
    zero_f<<<2, blk, 0, stream>>>(bns, 2 * HID_C);
    gemm_2t<HID_C, 0><<<ggrid, blk, 0, stream>>>(H, wBh, wBl, b2_0, Hb0, M_NODES, bns);
    bn_finalize<<<1, blk, 0, stream>>>(bns, g0, be0, ss0);

    // ---- Layer 1 ----
    gather_b16<HID_C, true><<<(M_NODES + 7) / 8, blk, 0, stream>>>(Hb0, rowptr, csr_src,
                                                                   ss0, A1);
    gemm_2t<HID_C, 1><<<ggrid, blk, 0, stream>>>(A1, wCh, wCl, b1_1, H2, M_NODES, nullptr);
    zero_f<<<2, blk, 0, stream>>>(bns, 2 * HID_C);
    gemm_2t<HID_C, 0><<<ggrid, blk, 0, stream>>>(H2, wDh, wDl, b2_1, Hb1, M_NODES, bns);
    bn_finalize<<<1, blk, 0, stream>>>(bns, g1, be1, ss1);

    // ---- Pool (fused BN+relu) ----
    zero_f<<<(N_GRAPHS_C * HID_C + 255) / 256, blk, 0, stream>>>(psum, N_GRAPHS_C * HID_C);
    pool_bn<<<POOL_BLOCKS, blk, 0, stream>>>(Hb1, ss1, batch, psum, M_NODES);
    pool_finalize<<<256, blk, 0, stream>>>(psum, batch, out);
}

// Round 8
// 610.481 us; speedup vs baseline: 8.0564x; 1.0140x over previous
//
#include <hip/hip_runtime.h>

#define M_NODES 100000
#define N_EDGES_C 800000
#define IN_DIM_C 128
#define HID_C 256
#define N_GRAPHS_C 256
#define BN_EPS_C 1e-5f

typedef __attribute__((ext_vector_type(8))) short short8v;
typedef __attribute__((ext_vector_type(4))) float floatx4;

__device__ __forceinline__ unsigned short bf16_rne(float f) {
    union { float f; unsigned u; } x; x.f = f;
    unsigned r = x.u + 0x7FFF + ((x.u >> 16) & 1);
    return (unsigned short)(r >> 16);
}
__device__ __forceinline__ float bf16_to_f(unsigned short h) {
    union { unsigned u; float f; } x; x.u = ((unsigned)h) << 16;
    return x.f;
}
__device__ __forceinline__ float bf16lo_f(unsigned u) {
    union { unsigned u; float f; } x; x.u = u << 16;
    return x.f;
}
__device__ __forceinline__ float bf16hi_f(unsigned u) {
    union { unsigned u; float f; } x; x.u = u & 0xffff0000u;
    return x.f;
}

// ---------------- small helpers ----------------
__global__ void zero_f(float* __restrict__ p, int n) {
    int i = blockIdx.x * blockDim.x + threadIdx.x;
    if (i < n) p[i] = 0.f;
}
__global__ void zero_i(int* __restrict__ p, int n) {
    int i = blockIdx.x * blockDim.x + threadIdx.x;
    if (i < n) p[i] = 0;
}
__global__ void copy_i(const int* __restrict__ s, int* __restrict__ d, int n) {
    int i = blockIdx.x * blockDim.x + threadIdx.x;
    if (i < n) d[i] = s[i];
}
__global__ void f2b(const float4* __restrict__ in, ushort4* __restrict__ out, int n4) {
    int i = blockIdx.x * blockDim.x + threadIdx.x;
    if (i >= n4) return;
    float4 v = in[i];
    ushort4 o;
    o.x = bf16_rne(v.x); o.y = bf16_rne(v.y); o.z = bf16_rne(v.z); o.w = bf16_rne(v.w);
    out[i] = o;
}

// ---------------- W transpose + bf16 hi/lo split ----------------
template <int K>
__global__ void wsplit(const float* __restrict__ W, unsigned short* __restrict__ hi,
                       unsigned short* __restrict__ lo) {
    int t = blockIdx.x * blockDim.x + threadIdx.x;
    if (t >= K * HID_C) return;
    int k = t % K, n = t / K;
    float w = W[(long long)k * HID_C + n];
    unsigned short h = bf16_rne(w);
    unsigned short l = bf16_rne(w - bf16_to_f(h));
    hi[(long long)n * K + k] = h;
    lo[(long long)n * K + k] = l;
}

// ---------------- CSR build ----------------
__global__ void csr_count(const int* __restrict__ dst, int* __restrict__ counts) {
    int e = blockIdx.x * blockDim.x + threadIdx.x;
    if (e < N_EDGES_C) atomicAdd(&counts[dst[e]], 1);
}

__global__ __launch_bounds__(256) void block_scan(const int* __restrict__ counts,
                                                  int* __restrict__ excl,
                                                  int* __restrict__ partials) {
    __shared__ int sm[256];
    int i = blockIdx.x * 256 + threadIdx.x;
    int v = (i < M_NODES) ? counts[i] : 0;
    sm[threadIdx.x] = v;
    __syncthreads();
    for (int off = 1; off < 256; off <<= 1) {
        int add = (threadIdx.x >= off) ? sm[threadIdx.x - off] : 0;
        __syncthreads();
        sm[threadIdx.x] += add;
        __syncthreads();
    }
    if (i <= M_NODES) excl[i] = sm[threadIdx.x] - v;
    if (threadIdx.x == 255) partials[blockIdx.x] = sm[255];
}

__global__ __launch_bounds__(512) void scan_partials(int* __restrict__ partials, int nb) {
    __shared__ int sm[512];
    int t = threadIdx.x;
    int v = (t < nb) ? partials[t] : 0;
    sm[t] = v;
    __syncthreads();
    for (int off = 1; off < 512; off <<= 1) {
        int add = (t >= off) ? sm[t - off] : 0;
        __syncthreads();
        sm[t] += add;
        __syncthreads();
    }
    if (t < nb) partials[t] = sm[t] - v;
}

__global__ void add_offsets(int* __restrict__ rowptr, const int* __restrict__ partials) {
    int i = blockIdx.x * 256 + threadIdx.x;
    if (i <= M_NODES) rowptr[i] += partials[blockIdx.x];
}

__global__ void csr_fill(const int* __restrict__ src, const int* __restrict__ dst,
                         int* __restrict__ fillpos, int* __restrict__ csr_src) {
    int e = blockIdx.x * blockDim.x + threadIdx.x;
    if (e >= N_EDGES_C) return;
    int pos = atomicAdd(&fillpos[dst[e]], 1);
    csr_src[pos] = src[e];
}

// ---------------- gather (bf16 in) + optional BN/relu -> bf16 out ----------------
template <int K, bool BN>
__global__ __launch_bounds__(256) void gather_b16(const unsigned short* __restrict__ h,
                                                  const int* __restrict__ rowptr,
                                                  const int* __restrict__ csr_src,
                                                  const float* __restrict__ ss,
                                                  unsigned short* __restrict__ outH) {
    constexpr int NE = K / 8;
    int node = blockIdx.x * (256 / NE) + threadIdx.x / NE;
    int q = threadIdx.x & (NE - 1);
    if (node >= M_NODES) return;
    int f = q * 8;
    float sc[8], sh[8];
    if (BN) {
#pragma unroll
        for (int i = 0; i < 8; ++i) { sc[i] = ss[f + i]; sh[i] = ss[HID_C + f + i]; }
    }
    float a[8];
    {
        uint4 u = *(const uint4*)(h + (long long)node * K + f);
        float t[8] = {bf16lo_f(u.x), bf16hi_f(u.x), bf16lo_f(u.y), bf16hi_f(u.y),
                      bf16lo_f(u.z), bf16hi_f(u.z), bf16lo_f(u.w), bf16hi_f(u.w)};
#pragma unroll
        for (int i = 0; i < 8; ++i)
            a[i] = BN ? fmaxf(fmaf(t[i], sc[i], sh[i]), 0.f) : t[i];
    }
    int beg = rowptr[node], end = rowptr[node + 1];
    for (int e = beg; e < end; ++e) {
        long long s = csr_src[e];
        uint4 u = *(const uint4*)(h + s * K + f);
        float t[8] = {bf16lo_f(u.x), bf16hi_f(u.x), bf16lo_f(u.y), bf16hi_f(u.y),
                      bf16lo_f(u.z), bf16hi_f(u.z), bf16lo_f(u.w), bf16hi_f(u.w)};
#pragma unroll
        for (int i = 0; i < 8; ++i)
            a[i] += BN ? fmaxf(fmaf(t[i], sc[i], sh[i]), 0.f) : t[i];
    }
    uint4 o;
    o.x = (unsigned)bf16_rne(a[0]) | ((unsigned)bf16_rne(a[1]) << 16);
    o.y = (unsigned)bf16_rne(a[2]) | ((unsigned)bf16_rne(a[3]) << 16);
    o.z = (unsigned)bf16_rne(a[4]) | ((unsigned)bf16_rne(a[5]) << 16);
    o.w = (unsigned)bf16_rne(a[6]) | ((unsigned)bf16_rne(a[7]) << 16);
    *(uint4*)(outH + (long long)node * K + f) = o;
}

// ---------------- fused MLP: out = (relu(A@W1+b1))@W2+b2, bf16 out + BN col sums ----------------
// 512 threads = 8 waves (2 row-halves x 4 col-quarters). BM=128 rows/block.
// Stage 1 -> 64KB swizzled LDS H tile; stage 2 reads A-frags from LDS.
template <int K>
__global__ __launch_bounds__(512, 2) void fused_mlp(const unsigned short* __restrict__ A,
                                                    const unsigned short* __restrict__ W1h,
                                                    const unsigned short* __restrict__ W1l,
                                                    const float* __restrict__ b1,
                                                    const unsigned short* __restrict__ W2h,
                                                    const unsigned short* __restrict__ W2l,
                                                    const float* __restrict__ b2,
                                                    unsigned short* __restrict__ outH,
                                                    int M, float* __restrict__ bnsums) {
    __shared__ char lds_raw[65536];

    const int tid = threadIdx.x;
    const int lane = tid & 63;
    const int wave = tid >> 6;       // 0..7
    const int wr = wave & 1;         // row 64-half
    const int wc = wave >> 1;        // col 64-quarter (0..3)
    const int gm = blockIdx.x * 128;
    const int kb = (lane >> 4) * 8;  // k element sub-block
    const int l15 = lane & 15;
    const int rgrp = (lane >> 4) * 4;

    floatx4 acc[4][4];
#pragma unroll
    for (int i = 0; i < 4; ++i)
#pragma unroll
        for (int j = 0; j < 4; ++j) acc[i][j] = (floatx4){0.f, 0.f, 0.f, 0.f};

    // ---------- stage 1: H = relu(A@W1+b1) ----------
    long long arow[4], bcol1[4];
#pragma unroll
    for (int i = 0; i < 4; ++i) {
        int row = gm + wr * 64 + i * 16 + l15;
        if (row >= M) row = M - 1;
        arow[i] = (long long)row * K + kb;
    }
#pragma unroll
    for (int j = 0; j < 4; ++j)
        bcol1[j] = (long long)(wc * 64 + j * 16 + l15) * K + kb;

#pragma unroll
    for (int k0 = 0; k0 < K; k0 += 32) {
        short8v af[4], bh[4], bl[4];
#pragma unroll
        for (int i = 0; i < 4; ++i)
            af[i] = *(const short8v*)(A + arow[i] + k0);
#pragma unroll
        for (int j = 0; j < 4; ++j) {
            bh[j] = *(const short8v*)(W1h + bcol1[j] + k0);
            bl[j] = *(const short8v*)(W1l + bcol1[j] + k0);
        }
#pragma unroll
        for (int i = 0; i < 4; ++i)
#pragma unroll
            for (int j = 0; j < 4; ++j) {
                acc[i][j] = __builtin_amdgcn_mfma_f32_16x16x32_bf16(af[i], bh[j], acc[i][j], 0, 0, 0);
                acc[i][j] = __builtin_amdgcn_mfma_f32_16x16x32_bf16(af[i], bl[j], acc[i][j], 0, 0, 0);
            }
    }

    // write relu'd bf16 H tile into swizzled LDS [128][256]
#pragma unroll
    for (int j = 0; j < 4; ++j) {
        int col = wc * 64 + j * 16 + l15;
        float bb = b1[col];
#pragma unroll
        for (int i = 0; i < 4; ++i) {
            int lrow = wr * 64 + i * 16 + rgrp;
#pragma unroll
            for (int r = 0; r < 4; ++r) {
                int row = lrow + r;
                float v = fmaxf(acc[i][j][r] + bb, 0.f);
                int bo = (row * 512 + col * 2) ^ ((row & 7) << 4);
                *(unsigned short*)(lds_raw + bo) = bf16_rne(v);
            }
        }
    }
    __syncthreads();

    // ---------- stage 2: out = H@W2+b2 ----------
#pragma unroll
    for (int i = 0; i < 4; ++i)
#pragma unroll
        for (int j = 0; j < 4; ++j) acc[i][j] = (floatx4){0.f, 0.f, 0.f, 0.f};

    long long bcol2[4];
#pragma unroll
    for (int j = 0; j < 4; ++j)
        bcol2[j] = (long long)(wc * 64 + j * 16 + l15) * HID_C + kb;
    int hrow[4];
#pragma unroll
    for (int i = 0; i < 4; ++i) hrow[i] = wr * 64 + i * 16 + l15;

#pragma unroll
    for (int k0 = 0; k0 < HID_C; k0 += 32) {
        short8v af[4], bh[4], bl[4];
#pragma unroll
        for (int i = 0; i < 4; ++i) {
            int bo = (hrow[i] * 512 + (k0 + kb) * 2) ^ ((hrow[i] & 7) << 4);
            af[i] = *(const short8v*)(lds_raw + bo);
        }
#pragma unroll
        for (int j = 0; j < 4; ++j) {
            bh[j] = *(const short8v*)(W2h + bcol2[j] + k0);
            bl[j] = *(const short8v*)(W2l + bcol2[j] + k0);
        }
#pragma unroll
        for (int i = 0; i < 4; ++i)
#pragma unroll
            for (int j = 0; j < 4; ++j) {
                acc[i][j] = __builtin_amdgcn_mfma_f32_16x16x32_bf16(af[i], bh[j], acc[i][j], 0, 0, 0);
                acc[i][j] = __builtin_amdgcn_mfma_f32_16x16x32_bf16(af[i], bl[j], acc[i][j], 0, 0, 0);
            }
    }

    // fused BN column sums (exact fp32 from accumulators)
#pragma unroll
    for (int j = 0; j < 4; ++j) {
        int col = wc * 64 + j * 16 + l15;
        float bb = b2[col];
        float s1 = 0.f, s2 = 0.f;
#pragma unroll
        for (int i = 0; i < 4; ++i) {
            int rowb = gm + wr * 64 + i * 16 + rgrp;
#pragma unroll
            for (int r = 0; r < 4; ++r) {
                if (rowb + r < M) {
                    float v = acc[i][j][r] + bb;
                    s1 += v; s2 += v * v;
                }
            }
        }
        s1 += __shfl_xor(s1, 16); s1 += __shfl_xor(s1, 32);
        s2 += __shfl_xor(s2, 16); s2 += __shfl_xor(s2, 32);
        if ((lane >> 4) == 0) {
            atomicAdd(&bnsums[col], s1);
            atomicAdd(&bnsums[HID_C + col], s2);
        }
    }

    // coalesced bf16 epilogue via LDS (reuse lds_raw; H is dead), 2 col-half phases
    unsigned short* stg = (unsigned short*)lds_raw;  // [128][132]
#pragma unroll
    for (int p = 0; p < 2; ++p) {
        __syncthreads();
        if ((wc >> 1) == p) {
#pragma unroll
            for (int j = 0; j < 4; ++j) {
                int col = wc * 64 + j * 16 + l15;
                int lcol = (wc & 1) * 64 + j * 16 + l15;
                float bb = b2[col];
#pragma unroll
                for (int i = 0; i < 4; ++i) {
                    int lrow = wr * 64 + i * 16 + rgrp;
#pragma unroll
                    for (int r = 0; r < 4; ++r)
                        stg[(lrow + r) * 132 + lcol] = bf16_rne(acc[i][j][r] + bb);
                }
            }
        }
        __syncthreads();
#pragma unroll
        for (int it = 0; it < 8; ++it) {
            int idx = it * 512 + tid;
            int row = idx >> 5;
            int c4 = idx & 31;
            int grow = gm + row;
            if (grow < M)
                *(ushort4*)(outH + (long long)grow * HID_C + p * 128 + c4 * 4) =
                    *(const ushort4*)&stg[row * 132 + c4 * 4];
        }
    }
}

// ---------------- BatchNorm finalize ----------------
__global__ void bn_finalize(const float* __restrict__ sums, const float* __restrict__ gamma,
                            const float* __restrict__ beta, float* __restrict__ ss) {
    int f = threadIdx.x;
    float mean = sums[f] * (1.0f / M_NODES);
    float var = sums[HID_C + f] * (1.0f / M_NODES) - mean * mean;
    float sc = gamma[f] * rsqrtf(var + BN_EPS_C);
    ss[f] = sc;
    ss[HID_C + f] = beta[f] - mean * sc;
}

// ---------------- pooling (bf16 in, fused BN+relu) ----------------
#define POOL_BLOCKS 4096
#define POOL_RPB 25
__global__ void pool_bn(const unsigned short* __restrict__ h, const float* __restrict__ ss,
                        const int* __restrict__ batch, float* __restrict__ sums, int M) {
    int f = threadIdx.x;
    float sc = ss[f], sh = ss[HID_C + f];
    int r0 = blockIdx.x * POOL_RPB;
    if (r0 >= M) return;
    int r1 = r0 + POOL_RPB;
    if (r1 > M) r1 = M;
    int cur = batch[r0];
    float acc = 0.f;
    for (int r = r0; r < r1; ++r) {
        int g = batch[r];
        if (g != cur) {
            atomicAdd(&sums[(long long)cur * HID_C + f], acc);
            acc = 0.f;
            cur = g;
        }
        float v = bf16_to_f(h[(long long)r * HID_C + f]);
        acc += fmaxf(fmaf(v, sc, sh), 0.f);
    }
    atomicAdd(&sums[(long long)cur * HID_C + f], acc);
}

__device__ __forceinline__ int lower_bound_i(const int* a, int n, int v) {
    int lo = 0, hi = n;
    while (lo < hi) {
        int mid = (lo + hi) >> 1;
        if (a[mid] < v) lo = mid + 1;
        else hi = mid;
    }
    return lo;
}

__global__ void pool_finalize(const float* __restrict__ sums, const int* __restrict__ batch,
                              float* __restrict__ out) {
    int g = blockIdx.x, f = threadIdx.x;
    int lb = lower_bound_i(batch, M_NODES, g);
    int ub = lower_bound_i(batch, M_NODES, g + 1);
    float cnt = (float)(ub - lb);
    out[(long long)g * HID_C + f] = sums[(long long)g * HID_C + f] / fmaxf(cnt, 1.0f);
}

// ---------------- launch ----------------
extern "C" void kernel_launch(void* const* d_in, const int* in_sizes, int n_in,
                              void* d_out, int out_size, void* d_ws, size_t ws_size,
                              hipStream_t stream) {
    const float* x = (const float*)d_in[0];
    const int* ei = (const int*)d_in[1];
    const int* esrc = ei;
    const int* edst = ei + N_EDGES_C;
    const int* batch = (const int*)d_in[2];
    const float* W1_0 = (const float*)d_in[3];
    const float* b1_0 = (const float*)d_in[4];
    const float* W2_0 = (const float*)d_in[5];
    const float* b2_0 = (const float*)d_in[6];
    const float* g0 = (const float*)d_in[7];
    const float* be0 = (const float*)d_in[8];
    const float* W1_1 = (const float*)d_in[9];
    const float* b1_1 = (const float*)d_in[10];
    const float* W2_1 = (const float*)d_in[11];
    const float* b2_1 = (const float*)d_in[12];
    const float* g1 = (const float*)d_in[13];
    const float* be1 = (const float*)d_in[14];
    float* out = (float*)d_out;

    const long long NF = (long long)M_NODES * HID_C;      // 25.6M
    const long long NI = (long long)M_NODES * IN_DIM_C;   // 12.8M
    unsigned short* U = (unsigned short*)d_ws;
    unsigned short* X16 = U;                 // NI
    unsigned short* A0 = U + NI;             // NI
    unsigned short* Hb0 = U + 2 * NI;        // NF  (pre-BN out, layer 0)
    unsigned short* A1 = Hb0 + NF;           // NF
    unsigned short* Hb1 = A1 + NF;           // NF  (pre-BN out, layer 1)
    float* fbase = (float*)(Hb1 + NF);
    float* bns = fbase;                          // 512
    float* ss0 = bns + 2 * HID_C;                // 512
    float* ss1 = ss0 + 2 * HID_C;                // 512
    float* psum = ss1 + 2 * HID_C;               // 65536
    int* counts = (int*)(psum + N_GRAPHS_C * HID_C);  // 100352
    int* partials = counts + 100352;             // 512
    int* rowptr = partials + 512;                // 100004
    int* csr_src = rowptr + 100004;              // 800000
    unsigned short* wp = (unsigned short*)(csr_src + N_EDGES_C);
    unsigned short* wAh = wp;
    unsigned short* wAl = wAh + IN_DIM_C * HID_C;
    unsigned short* wBh = wAl + IN_DIM_C * HID_C;
    unsigned short* wBl = wBh + HID_C * HID_C;
    unsigned short* wCh = wBl + HID_C * HID_C;
    unsigned short* wCl = wCh + HID_C * HID_C;
    unsigned short* wDh = wCl + HID_C * HID_C;
    unsigned short* wDl = wDh + HID_C * HID_C;

    dim3 blk(256);
    dim3 fgrid((M_NODES + 127) / 128);

    // ---- W splits ----
    wsplit<IN_DIM_C><<<(IN_DIM_C * HID_C + 255) / 256, blk, 0, stream>>>(W1_0, wAh, wAl);
    wsplit<HID_C><<<(HID_C * HID_C + 255) / 256, blk, 0, stream>>>(W2_0, wBh, wBl);
    wsplit<HID_C><<<(HID_C * HID_C + 255) / 256, blk, 0, stream>>>(W1_1, wCh, wCl);
    wsplit<HID_C><<<(HID_C * HID_C + 255) / 256, blk, 0, stream>>>(W2_1, wDh, wDl);

    // ---- CSR build ----
    zero_i<<<(M_NODES + 255) / 256, blk, 0, stream>>>(counts, M_NODES);
    csr_count<<<(N_EDGES_C + 255) / 256, blk, 0, stream>>>(edst, counts);
    block_scan<<<392, blk, 0, stream>>>(counts, rowptr, partials);
    scan_partials<<<1, 512, 0, stream>>>(partials, 392);
    add_offsets<<<392, blk, 0, stream>>>(rowptr, partials);
    copy_i<<<(M_NODES + 255) / 256, blk, 0, stream>>>(rowptr, counts, M_NODES);
    csr_fill<<<(N_EDGES_C + 255) / 256, blk, 0, stream>>>(esrc, edst, counts, csr_src);

    // ---- x -> bf16 ----
    f2b<<<(int)((NI / 4 + 255) / 256), blk, 0, stream>>>((const float4*)x, (ushort4*)X16,
                                                         (int)(NI / 4));

    // ---- Layer 0 ----
    gather_b16<IN_DIM_C, false><<<(M_NODES + 15) / 16, blk, 0, stream>>>(X16, rowptr, csr_src,
                                                                         nullptr, A0);
    zero_f<<<2, blk, 0, stream>>>(bns, 2 * HID_C);
    fused_mlp<IN_DIM_C><<<fgrid, dim3(512), 0, stream>>>(A0, wAh, wAl, b1_0, wBh, wBl, b2_0,
                                                         Hb0, M_NODES, bns);
    bn_finalize<<<1, blk, 0, stream>>>(bns, g0, be0, ss0);

    // ---- Layer 1 ----
    gather_b16<HID_C, true><<<(M_NODES + 7) / 8, blk, 0, stream>>>(Hb0, rowptr, csr_src,
                                                                   ss0, A1);
    zero_f<<<2, blk, 0, stream>>>(bns, 2 * HID_C);
    fused_mlp<HID_C><<<fgrid, dim3(512), 0, stream>>>(A1, wCh, wCl, b1_1, wDh, wDl, b2_1,
                                                      Hb1, M_NODES, bns);
    bn_finalize<<<1, blk, 0, stream>>>(bns, g1, be1, ss1);

    // ---- Pool (fused BN+relu) ----
    zero_f<<<(N_GRAPHS_C * HID_C + 255) / 256, blk, 0, stream>>>(psum, N_GRAPHS_C * HID_C);
    pool_bn<<<POOL_BLOCKS, blk, 0, stream>>>(Hb1, ss1, batch, psum, M_NODES);
    pool_finalize<<<256, blk, 0, stream>>>(psum, batch, out);
}

// Round 9
// 459.408 us; speedup vs baseline: 10.7056x; 1.3288x over previous
//
#include <hip/hip_runtime.h>

#define M_NODES 100000
#define N_EDGES_C 800000
#define IN_DIM_C 128
#define HID_C 256
#define N_GRAPHS_C 256
#define BN_EPS_C 1e-5f

typedef __attribute__((ext_vector_type(8))) short short8v;
typedef __attribute__((ext_vector_type(4))) float floatx4;

__device__ __forceinline__ unsigned short bf16_rne(float f) {
    union { float f; unsigned u; } x; x.f = f;
    unsigned r = x.u + 0x7FFF + ((x.u >> 16) & 1);
    return (unsigned short)(r >> 16);
}
__device__ __forceinline__ float bf16_to_f(unsigned short h) {
    union { unsigned u; float f; } x; x.u = ((unsigned)h) << 16;
    return x.f;
}
__device__ __forceinline__ float bf16lo_f(unsigned u) {
    union { unsigned u; float f; } x; x.u = u << 16;
    return x.f;
}
__device__ __forceinline__ float bf16hi_f(unsigned u) {
    union { unsigned u; float f; } x; x.u = u & 0xffff0000u;
    return x.f;
}

// fragment-major W offset: c = output col (0..255), k = reduction idx (0..K-1)
// off = ((k>>5)*16 + (c>>4))*512 + ((k>>3)&3)*128 + (c&15)*8 + (k&7)
// -> one wave k-step load (64 lanes x 16B) is a single contiguous 1KB segment.
template <int K>
__device__ __forceinline__ long long woff(int c, int k) {
    return ((long long)((k >> 5) * 16 + (c >> 4))) * 512 + ((k >> 3) & 3) * 128 +
           (c & 15) * 8 + (k & 7);
}

// ---------------- small helpers ----------------
__global__ void zero_f(float* __restrict__ p, int n) {
    int i = blockIdx.x * blockDim.x + threadIdx.x;
    if (i < n) p[i] = 0.f;
}
__global__ void zero_i(int* __restrict__ p, int n) {
    int i = blockIdx.x * blockDim.x + threadIdx.x;
    if (i < n) p[i] = 0;
}
__global__ void copy_i(const int* __restrict__ s, int* __restrict__ d, int n) {
    int i = blockIdx.x * blockDim.x + threadIdx.x;
    if (i < n) d[i] = s[i];
}
__global__ void f2b(const float4* __restrict__ in, ushort4* __restrict__ out, int n4) {
    int i = blockIdx.x * blockDim.x + threadIdx.x;
    if (i >= n4) return;
    float4 v = in[i];
    ushort4 o;
    o.x = bf16_rne(v.x); o.y = bf16_rne(v.y); o.z = bf16_rne(v.z); o.w = bf16_rne(v.w);
    out[i] = o;
}

// ---------------- W split -> fragment-major hi/lo planes ----------------
template <int K>
__global__ void wsplit(const float* __restrict__ W, unsigned short* __restrict__ hi,
                       unsigned short* __restrict__ lo) {
    int t = blockIdx.x * blockDim.x + threadIdx.x;
    if (t >= K * HID_C) return;
    int k = t % K, c = t / K;
    float w = W[(long long)k * HID_C + c];
    unsigned short h = bf16_rne(w);
    unsigned short l = bf16_rne(w - bf16_to_f(h));
    long long o = woff<K>(c, k);
    hi[o] = h;
    lo[o] = l;
}

// ---------------- CSR build ----------------
__global__ void csr_count(const int* __restrict__ dst, int* __restrict__ counts) {
    int e = blockIdx.x * blockDim.x + threadIdx.x;
    if (e < N_EDGES_C) atomicAdd(&counts[dst[e]], 1);
}

__global__ __launch_bounds__(256) void block_scan(const int* __restrict__ counts,
                                                  int* __restrict__ excl,
                                                  int* __restrict__ partials) {
    __shared__ int sm[256];
    int i = blockIdx.x * 256 + threadIdx.x;
    int v = (i < M_NODES) ? counts[i] : 0;
    sm[threadIdx.x] = v;
    __syncthreads();
    for (int off = 1; off < 256; off <<= 1) {
        int add = (threadIdx.x >= off) ? sm[threadIdx.x - off] : 0;
        __syncthreads();
        sm[threadIdx.x] += add;
        __syncthreads();
    }
    if (i <= M_NODES) excl[i] = sm[threadIdx.x] - v;
    if (threadIdx.x == 255) partials[blockIdx.x] = sm[255];
}

__global__ __launch_bounds__(512) void scan_partials(int* __restrict__ partials, int nb) {
    __shared__ int sm[512];
    int t = threadIdx.x;
    int v = (t < nb) ? partials[t] : 0;
    sm[t] = v;
    __syncthreads();
    for (int off = 1; off < 512; off <<= 1) {
        int add = (t >= off) ? sm[t - off] : 0;
        __syncthreads();
        sm[t] += add;
        __syncthreads();
    }
    if (t < nb) partials[t] = sm[t] - v;
}

__global__ void add_offsets(int* __restrict__ rowptr, const int* __restrict__ partials) {
    int i = blockIdx.x * 256 + threadIdx.x;
    if (i <= M_NODES) rowptr[i] += partials[blockIdx.x];
}

__global__ void csr_fill(const int* __restrict__ src, const int* __restrict__ dst,
                         int* __restrict__ fillpos, int* __restrict__ csr_src) {
    int e = blockIdx.x * blockDim.x + threadIdx.x;
    if (e >= N_EDGES_C) return;
    int pos = atomicAdd(&fillpos[dst[e]], 1);
    csr_src[pos] = src[e];
}

// ---------------- gather (bf16 normal-layout in) -> fragment-major bf16 A ----------------
// A layout: off(row,k) = ((row>>4)*(K/8) + (k>>3))*128 + (row&15)*8 + (k&7)
// block = 16 nodes x 16 feature-chunk threads (CH chunks of 8 feats per thread).
template <int K, bool BN>
__global__ __launch_bounds__(256) void gather_frag(const unsigned short* __restrict__ h,
                                                   const int* __restrict__ rowptr,
                                                   const int* __restrict__ csr_src,
                                                   const float* __restrict__ ss,
                                                   unsigned short* __restrict__ outA) {
    constexpr int CH = K / 128;  // 1 (K=128) or 2 (K=256)
    const int nlow = threadIdx.x & 15;
    const int q = threadIdx.x >> 4;  // 0..15
    const int node = blockIdx.x * 16 + nlow;
    if (node >= M_NODES) return;

    float a[CH][8];
    float sc[CH][8], sh[CH][8];
    if (BN) {
#pragma unroll
        for (int cc = 0; cc < CH; ++cc)
#pragma unroll
            for (int i = 0; i < 8; ++i) {
                int f = cc * 128 + q * 8 + i;
                sc[cc][i] = ss[f];
                sh[cc][i] = ss[HID_C + f];
            }
    }
    // self term
#pragma unroll
    for (int cc = 0; cc < CH; ++cc) {
        uint4 u = *(const uint4*)(h + (long long)node * K + cc * 128 + q * 8);
        float t[8] = {bf16lo_f(u.x), bf16hi_f(u.x), bf16lo_f(u.y), bf16hi_f(u.y),
                      bf16lo_f(u.z), bf16hi_f(u.z), bf16lo_f(u.w), bf16hi_f(u.w)};
#pragma unroll
        for (int i = 0; i < 8; ++i)
            a[cc][i] = BN ? fmaxf(fmaf(t[i], sc[cc][i], sh[cc][i]), 0.f) : t[i];
    }
    int beg = rowptr[node], end = rowptr[node + 1];
    for (int e = beg; e < end; ++e) {
        long long s = csr_src[e];
#pragma unroll
        for (int cc = 0; cc < CH; ++cc) {
            uint4 u = *(const uint4*)(h + s * K + cc * 128 + q * 8);
            float t[8] = {bf16lo_f(u.x), bf16hi_f(u.x), bf16lo_f(u.y), bf16hi_f(u.y),
                          bf16lo_f(u.z), bf16hi_f(u.z), bf16lo_f(u.w), bf16hi_f(u.w)};
#pragma unroll
            for (int i = 0; i < 8; ++i)
                a[cc][i] += BN ? fmaxf(fmaf(t[i], sc[cc][i], sh[cc][i]), 0.f) : t[i];
        }
    }
#pragma unroll
    for (int cc = 0; cc < CH; ++cc) {
        uint4 o;
        o.x = (unsigned)bf16_rne(a[cc][0]) | ((unsigned)bf16_rne(a[cc][1]) << 16);
        o.y = (unsigned)bf16_rne(a[cc][2]) | ((unsigned)bf16_rne(a[cc][3]) << 16);
        o.z = (unsigned)bf16_rne(a[cc][4]) | ((unsigned)bf16_rne(a[cc][5]) << 16);
        o.w = (unsigned)bf16_rne(a[cc][6]) | ((unsigned)bf16_rne(a[cc][7]) << 16);
        long long off = ((long long)(node >> 4) * (K / 8) + cc * 16 + q) * 128 + nlow * 8;
        *(uint4*)(outA + off) = o;
    }
}

// ---------------- fused MLP, fragment-major operands, BM=64, 256 thr, 32KB LDS ----------------
// out = (relu(A@W1+b1))@W2+b2 -> bf16 normal layout + fused BN column sums.
template <int K>
__global__ __launch_bounds__(256, 4) void fused_mlp(const unsigned short* __restrict__ A,
                                                    const unsigned short* __restrict__ W1h,
                                                    const unsigned short* __restrict__ W1l,
                                                    const float* __restrict__ b1,
                                                    const unsigned short* __restrict__ W2h,
                                                    const unsigned short* __restrict__ W2l,
                                                    const float* __restrict__ b2,
                                                    unsigned short* __restrict__ outH,
                                                    int M, float* __restrict__ bnsums) {
    __shared__ char lds_raw[32768];  // H tile: 64 rows x 256 cols bf16, XOR-swizzled

    const int tid = threadIdx.x;
    const int lane = tid & 63;
    const int wc = tid >> 6;          // 0..3: 64-col quarter
    const int gm = blockIdx.x * 64;
    const int l15 = lane & 15;
    const int kgrp = lane >> 4;       // 0..3
    const int rgrp = kgrp * 4;
    const int laneoff = kgrp * 128 + l15 * 8;  // element offset within a 1KB segment
    const int wquarter = wc * 4;

    floatx4 acc[4][4];
#pragma unroll
    for (int i = 0; i < 4; ++i)
#pragma unroll
        for (int j = 0; j < 4; ++j) acc[i][j] = (floatx4){0.f, 0.f, 0.f, 0.f};

    // ---------- stage 1: H = relu(A@W1+b1) ----------
    long long aseg[4];
#pragma unroll
    for (int i = 0; i < 4; ++i) {
        int rt = (gm >> 4) + i;
        if (rt > M / 16 - 1) rt = M / 16 - 1;
        aseg[i] = (long long)rt * (K / 8) * 128;
    }

#pragma unroll
    for (int k0 = 0; k0 < K; k0 += 32) {
        short8v af[4], bh[4], bl[4];
#pragma unroll
        for (int i = 0; i < 4; ++i)
            af[i] = *(const short8v*)(A + aseg[i] + k0 * 16 + laneoff);
#pragma unroll
        for (int j = 0; j < 4; ++j) {
            long long wb = (long long)(k0 >> 5) * 8192 + (wquarter + j) * 512 + laneoff;
            bh[j] = *(const short8v*)(W1h + wb);
            bl[j] = *(const short8v*)(W1l + wb);
        }
#pragma unroll
        for (int i = 0; i < 4; ++i)
#pragma unroll
            for (int j = 0; j < 4; ++j) {
                acc[i][j] = __builtin_amdgcn_mfma_f32_16x16x32_bf16(af[i], bh[j], acc[i][j], 0, 0, 0);
                acc[i][j] = __builtin_amdgcn_mfma_f32_16x16x32_bf16(af[i], bl[j], acc[i][j], 0, 0, 0);
            }
    }

    // write relu'd bf16 H tile into swizzled LDS [64][256]
#pragma unroll
    for (int j = 0; j < 4; ++j) {
        int col = wc * 64 + j * 16 + l15;
        float bb = b1[col];
#pragma unroll
        for (int i = 0; i < 4; ++i) {
            int lrow = i * 16 + rgrp;
#pragma unroll
            for (int r = 0; r < 4; ++r) {
                int row = lrow + r;
                float v = fmaxf(acc[i][j][r] + bb, 0.f);
                int bo = (row * 512 + col * 2) ^ ((row & 7) << 4);
                *(unsigned short*)(lds_raw + bo) = bf16_rne(v);
            }
        }
    }
    __syncthreads();

    // ---------- stage 2: out = H@W2+b2 ----------
#pragma unroll
    for (int i = 0; i < 4; ++i)
#pragma unroll
        for (int j = 0; j < 4; ++j) acc[i][j] = (floatx4){0.f, 0.f, 0.f, 0.f};

#pragma unroll
    for (int k0 = 0; k0 < HID_C; k0 += 32) {
        short8v af[4], bh[4], bl[4];
#pragma unroll
        for (int i = 0; i < 4; ++i) {
            int row = i * 16 + l15;
            int bo = (row * 512 + (k0 + kgrp * 8) * 2) ^ ((row & 7) << 4);
            af[i] = *(const short8v*)(lds_raw + bo);
        }
#pragma unroll
        for (int j = 0; j < 4; ++j) {
            long long wb = (long long)(k0 >> 5) * 8192 + (wquarter + j) * 512 + laneoff;
            bh[j] = *(const short8v*)(W2h + wb);
            bl[j] = *(const short8v*)(W2l + wb);
        }
#pragma unroll
        for (int i = 0; i < 4; ++i)
#pragma unroll
            for (int j = 0; j < 4; ++j) {
                acc[i][j] = __builtin_amdgcn_mfma_f32_16x16x32_bf16(af[i], bh[j], acc[i][j], 0, 0, 0);
                acc[i][j] = __builtin_amdgcn_mfma_f32_16x16x32_bf16(af[i], bl[j], acc[i][j], 0, 0, 0);
            }
    }

    // fused BN column sums (exact fp32 from accumulators)
#pragma unroll
    for (int j = 0; j < 4; ++j) {
        int col = wc * 64 + j * 16 + l15;
        float bb = b2[col];
        float s1 = 0.f, s2 = 0.f;
#pragma unroll
        for (int i = 0; i < 4; ++i) {
            int rowb = gm + i * 16 + rgrp;
#pragma unroll
            for (int r = 0; r < 4; ++r) {
                if (rowb + r < M) {
                    float v = acc[i][j][r] + bb;
                    s1 += v; s2 += v * v;
                }
            }
        }
        s1 += __shfl_xor(s1, 16); s1 += __shfl_xor(s1, 32);
        s2 += __shfl_xor(s2, 16); s2 += __shfl_xor(s2, 32);
        if ((lane >> 4) == 0) {
            atomicAdd(&bnsums[col], s1);
            atomicAdd(&bnsums[HID_C + col], s2);
        }
    }

    // coalesced bf16 epilogue via LDS (reuse lds_raw), 2 col-half phases
    unsigned short* stg = (unsigned short*)lds_raw;  // [64][132]
#pragma unroll
    for (int p = 0; p < 2; ++p) {
        __syncthreads();
        if ((wc >> 1) == p) {
#pragma unroll
            for (int j = 0; j < 4; ++j) {
                int col = wc * 64 + j * 16 + l15;
                int lcol = (wc & 1) * 64 + j * 16 + l15;
                float bb = b2[col];
#pragma unroll
                for (int i = 0; i < 4; ++i) {
                    int lrow = i * 16 + rgrp;
#pragma unroll
                    for (int r = 0; r < 4; ++r)
                        stg[(lrow + r) * 132 + lcol] = bf16_rne(acc[i][j][r] + bb);
                }
            }
        }
        __syncthreads();
#pragma unroll
        for (int it = 0; it < 8; ++it) {
            int idx = it * 256 + tid;
            int row = idx >> 5;
            int c4 = idx & 31;
            int grow = gm + row;
            if (grow < M)
                *(ushort4*)(outH + (long long)grow * HID_C + p * 128 + c4 * 4) =
                    *(const ushort4*)&stg[row * 132 + c4 * 4];
        }
    }
}

// ---------------- BatchNorm finalize ----------------
__global__ void bn_finalize(const float* __restrict__ sums, const float* __restrict__ gamma,
                            const float* __restrict__ beta, float* __restrict__ ss) {
    int f = threadIdx.x;
    float mean = sums[f] * (1.0f / M_NODES);
    float var = sums[HID_C + f] * (1.0f / M_NODES) - mean * mean;
    float sc = gamma[f] * rsqrtf(var + BN_EPS_C);
    ss[f] = sc;
    ss[HID_C + f] = beta[f] - mean * sc;
}

// ---------------- pooling (bf16 in, fused BN+relu) ----------------
#define POOL_BLOCKS 4096
#define POOL_RPB 25
__global__ void pool_bn(const unsigned short* __restrict__ h, const float* __restrict__ ss,
                        const int* __restrict__ batch, float* __restrict__ sums, int M) {
    int f = threadIdx.x;
    float sc = ss[f], sh = ss[HID_C + f];
    int r0 = blockIdx.x * POOL_RPB;
    if (r0 >= M) return;
    int r1 = r0 + POOL_RPB;
    if (r1 > M) r1 = M;
    int cur = batch[r0];
    float acc = 0.f;
    for (int r = r0; r < r1; ++r) {
        int g = batch[r];
        if (g != cur) {
            atomicAdd(&sums[(long long)cur * HID_C + f], acc);
            acc = 0.f;
            cur = g;
        }
        float v = bf16_to_f(h[(long long)r * HID_C + f]);
        acc += fmaxf(fmaf(v, sc, sh), 0.f);
    }
    atomicAdd(&sums[(long long)cur * HID_C + f], acc);
}

__device__ __forceinline__ int lower_bound_i(const int* a, int n, int v) {
    int lo = 0, hi = n;
    while (lo < hi) {
        int mid = (lo + hi) >> 1;
        if (a[mid] < v) lo = mid + 1;
        else hi = mid;
    }
    return lo;
}

__global__ void pool_finalize(const float* __restrict__ sums, const int* __restrict__ batch,
                              float* __restrict__ out) {
    int g = blockIdx.x, f = threadIdx.x;
    int lb = lower_bound_i(batch, M_NODES, g);
    int ub = lower_bound_i(batch, M_NODES, g + 1);
    float cnt = (float)(ub - lb);
    out[(long long)g * HID_C + f] = sums[(long long)g * HID_C + f] / fmaxf(cnt, 1.0f);
}

// ---------------- launch ----------------
extern "C" void kernel_launch(void* const* d_in, const int* in_sizes, int n_in,
                              void* d_out, int out_size, void* d_ws, size_t ws_size,
                              hipStream_t stream) {
    const float* x = (const float*)d_in[0];
    const int* ei = (const int*)d_in[1];
    const int* esrc = ei;
    const int* edst = ei + N_EDGES_C;
    const int* batch = (const int*)d_in[2];
    const float* W1_0 = (const float*)d_in[3];
    const float* b1_0 = (const float*)d_in[4];
    const float* W2_0 = (const float*)d_in[5];
    const float* b2_0 = (const float*)d_in[6];
    const float* g0 = (const float*)d_in[7];
    const float* be0 = (const float*)d_in[8];
    const float* W1_1 = (const float*)d_in[9];
    const float* b1_1 = (const float*)d_in[10];
    const float* W2_1 = (const float*)d_in[11];
    const float* b2_1 = (const float*)d_in[12];
    const float* g1 = (const float*)d_in[13];
    const float* be1 = (const float*)d_in[14];
    float* out = (float*)d_out;

    const long long NF = (long long)M_NODES * HID_C;      // 25.6M
    const long long NI = (long long)M_NODES * IN_DIM_C;   // 12.8M
    unsigned short* U = (unsigned short*)d_ws;
    unsigned short* X16 = U;                 // NI  (bf16 x, normal layout)
    unsigned short* A0 = U + NI;             // NI  (frag-major)
    unsigned short* Hb0 = U + 2 * NI;        // NF  (pre-BN out L0, normal layout)
    unsigned short* A1 = Hb0 + NF;           // NF  (frag-major)
    unsigned short* Hb1 = A1 + NF;           // NF  (pre-BN out L1, normal layout)
    float* fbase = (float*)(Hb1 + NF);
    float* bns = fbase;                          // 512
    float* ss0 = bns + 2 * HID_C;                // 512
    float* ss1 = ss0 + 2 * HID_C;                // 512
    float* psum = ss1 + 2 * HID_C;               // 65536
    int* counts = (int*)(psum + N_GRAPHS_C * HID_C);  // 100352
    int* partials = counts + 100352;             // 512
    int* rowptr = partials + 512;                // 100004
    int* csr_src = rowptr + 100004;              // 800000
    unsigned short* wp = (unsigned short*)(csr_src + N_EDGES_C);
    unsigned short* wAh = wp;
    unsigned short* wAl = wAh + IN_DIM_C * HID_C;
    unsigned short* wBh = wAl + IN_DIM_C * HID_C;
    unsigned short* wBl = wBh + HID_C * HID_C;
    unsigned short* wCh = wBl + HID_C * HID_C;
    unsigned short* wCl = wCh + HID_C * HID_C;
    unsigned short* wDh = wCl + HID_C * HID_C;
    unsigned short* wDl = wDh + HID_C * HID_C;

    dim3 blk(256);
    dim3 fgrid((M_NODES + 63) / 64);  // 1563

    // ---- W splits (fragment-major) ----
    wsplit<IN_DIM_C><<<(IN_DIM_C * HID_C + 255) / 256, blk, 0, stream>>>(W1_0, wAh, wAl);
    wsplit<HID_C><<<(HID_C * HID_C + 255) / 256, blk, 0, stream>>>(W2_0, wBh, wBl);
    wsplit<HID_C><<<(HID_C * HID_C + 255) / 256, blk, 0, stream>>>(W1_1, wCh, wCl);
    wsplit<HID_C><<<(HID_C * HID_C + 255) / 256, blk, 0, stream>>>(W2_1, wDh, wDl);

    // ---- CSR build ----
    zero_i<<<(M_NODES + 255) / 256, blk, 0, stream>>>(counts, M_NODES);
    csr_count<<<(N_EDGES_C + 255) / 256, blk, 0, stream>>>(edst, counts);
    block_scan<<<392, blk, 0, stream>>>(counts, rowptr, partials);
    scan_partials<<<1, 512, 0, stream>>>(partials, 392);
    add_offsets<<<392, blk, 0, stream>>>(rowptr, partials);
    copy_i<<<(M_NODES + 255) / 256, blk, 0, stream>>>(rowptr, counts, M_NODES);
    csr_fill<<<(N_EDGES_C + 255) / 256, blk, 0, stream>>>(esrc, edst, counts, csr_src);

    // ---- x -> bf16 ----
    f2b<<<(int)((NI / 4 + 255) / 256), blk, 0, stream>>>((const float4*)x, (ushort4*)X16,
                                                         (int)(NI / 4));

    // ---- Layer 0 ----
    gather_frag<IN_DIM_C, false><<<M_NODES / 16, blk, 0, stream>>>(X16, rowptr, csr_src,
                                                                   nullptr, A0);
    zero_f<<<2, blk, 0, stream>>>(bns, 2 * HID_C);
    fused_mlp<IN_DIM_C><<<fgrid, blk, 0, stream>>>(A0, wAh, wAl, b1_0, wBh, wBl, b2_0,
                                                   Hb0, M_NODES, bns);
    bn_finalize<<<1, blk, 0, stream>>>(bns, g0, be0, ss0);

    // ---- Layer 1 ----
    gather_frag<HID_C, true><<<M_NODES / 16, blk, 0, stream>>>(Hb0, rowptr, csr_src,
                                                               ss0, A1);
    zero_f<<<2, blk, 0, stream>>>(bns, 2 * HID_C);
    fused_mlp<HID_C><<<fgrid, blk, 0, stream>>>(A1, wCh, wCl, b1_1, wDh, wDl, b2_1,
                                                Hb1, M_NODES, bns);
    bn_finalize<<<1, blk, 0, stream>>>(bns, g1, be1, ss1);

    // ---- Pool (fused BN+relu) ----
    zero_f<<<(N_GRAPHS_C * HID_C + 255) / 256, blk, 0, stream>>>(psum, N_GRAPHS_C * HID_C);
    pool_bn<<<POOL_BLOCKS, blk, 0, stream>>>(Hb1, ss1, batch, psum, M_NODES);
    pool_finalize<<<256, blk, 0, stream>>>(psum, batch, out);
}